// Round 7
// baseline (116.130 us; speedup 1.0000x reference)
//
#include <hip/hip_runtime.h>
#include <hip/hip_bf16.h>

#define N_B   4
#define C_IN  128
#define HWSZ  4096
#define C_M   256

typedef __attribute__((ext_vector_type(8))) short          s16x8;   // bf16x8 frag (4 VGPR)
typedef __attribute__((ext_vector_type(8))) unsigned short u16x8;
typedef __attribute__((ext_vector_type(4))) unsigned short u16x4;
typedef __attribute__((ext_vector_type(4))) float          f32x4;

__device__ __forceinline__ unsigned short f2bf(float f) {
    union { float f; unsigned u; } v; v.f = f;
    unsigned r = v.u + 0x7fffu + ((v.u >> 16) & 1u);   // RNE
    return (unsigned short)(r >> 16);
}
__device__ __forceinline__ float bf2f(unsigned short u) {
    union { unsigned u; float f; } v; v.u = ((unsigned)u) << 16; return v.f;
}

// ---------------------------------------------------------------------------
// K1: fused prep. Blocks 0..255: img transpose (n,ci,h,w)->bf16 (n,h,w,ci).
// Blocks 256..2559: fragment-ordered weights.
//  w1f[z2][cc4][tap9][g9][lane64][j8]; row=g*16+(lane&15), ci=cc*32+(lane>>4)*8+j
//  w2f[uvt16][k9][ks8][lg4][ln16][j8] = 0.25*mk_w2[(k*256+uvt*16+ln)*256+ks*32+lg*8+j]
// ---------------------------------------------------------------------------
__global__ void __launch_bounds__(256)
prep_all(const float* __restrict__ img,
         const float* __restrict__ mk_w1, const float* __restrict__ fh_w1,
         const float* __restrict__ mk_w2,
         unsigned short* __restrict__ imgT,
         unsigned short* __restrict__ w1f, unsigned short* __restrict__ w2f)
{
    __shared__ float s[128][65];
    const int b = blockIdx.x;
    if (b < 256) {
        const int n = b >> 6, h = b & 63;
        const float* src = img + (size_t)n * C_IN * HWSZ + h * 64;
        for (int i = threadIdx.x; i < 128 * 64; i += 256) {
            int ci = i >> 6, w = i & 63;
            s[ci][w] = src[(size_t)ci * HWSZ + w];
        }
        __syncthreads();
        unsigned short* dst = imgT + ((size_t)(n * 64 + h) * 64) * 128;
        for (int i = threadIdx.x; i < 64 * 128; i += 256) {
            int w = i >> 7, ci = i & 127;
            dst[(size_t)w * 128 + ci] = f2bf(s[ci][w]);
        }
        return;
    }
    int i = (b - 256) * 256 + threadIdx.x;
    if (i < 2304 * 256) {
        int uvt = i / 36864;
        int r   = i - uvt * 36864;
        int k   = r / 4096;
        int r2  = r - k * 4096;
        int ks  = r2 >> 9;
        int lg  = (r2 >> 7) & 3;
        int ln  = (r2 >> 3) & 15;
        int j   = r2 & 7;
        w2f[i] = f2bf(0.25f * mk_w2[(size_t)(k * 256 + uvt * 16 + ln) * 256 + ks * 32 + lg * 8 + j]);
    }
    if (i < 2 * 4 * 9 * 9 * 512) {
        int z   = i / 165888;
        int r   = i - z * 165888;
        int cc  = r / 41472;
        int r2  = r - cc * 41472;
        int tap = r2 / 4608;
        int r3  = r2 - tap * 4608;
        int g   = r3 / 512;
        int r4  = r3 - g * 512;
        int lane = r4 >> 3, j = r4 & 7;
        int lg = lane >> 4, ln = lane & 15;
        int row = g * 16 + ln;
        int ci  = cc * 32 + lg * 8 + j;
        float w = 0.f;
        if (z == 0) {
            if (row < 128)      w = mk_w1[((size_t)row * C_IN + ci) * 9 + tap];
            else if (row < 130) w = fh_w1[((size_t)(row - 128) * C_IN + ci) * 9 + tap];
        } else {
            if (row < 128)      w = mk_w1[((size_t)(128 + row) * C_IN + ci) * 9 + tap];
        }
        w1f[i] = f2bf(w);
    }
}

// ---------------------------------------------------------------------------
// K2: conv1 implicit-GEMM 3x3. Grid 512 (XCD-swizzled (n,h,z)), 512 thr,
// 2 blocks/CU -> 4 waves/SIMD. Wave = (gq4, half2): q=2 px-groups, 2-3 g.
// Also computes per-block BN channel partials (fp32, deterministic).
// m_frag unit: [n][pxg256][ks8][lg4][ln16][j8], c = ks*32+lg*8+j.
// ---------------------------------------------------------------------------
__global__ void __launch_bounds__(512, 4)
conv1_mfma(const unsigned short* __restrict__ imgT,
           const unsigned short* __restrict__ w1f,
           const float* __restrict__ mk_b1, const float* __restrict__ fh_b1,
           unsigned short* __restrict__ m_frag, float* __restrict__ h_pre,
           float* __restrict__ ps_s, float* __restrict__ ps_s2)
{
    __shared__ unsigned short s_img[3][66][40];   // 15,840 B
    __shared__ float s_bias[144];
    __shared__ float s_ps[2][144], s_ps2[2][144];

    const int hw = blockIdx.x;
    const int xcd = hw & 7, slot = hw >> 3;
    const int lid = xcd * 64 + slot;
    const int n = lid >> 7, h = (lid >> 1) & 63, z = lid & 1;
    const int hn = n * 64 + h;

    const int tid = threadIdx.x;
    const int wv = tid >> 6, lane = tid & 63;
    const int lg = lane >> 4, ln = lane & 15;
    const int gq = wv >> 1, half = wv & 1;
    const int g0 = z ? (gq * 2) : ((int[4]){0, 3, 5, 7})[gq];
    const int gn = z ? 2 : ((int[4]){3, 2, 2, 2})[gq];

    if (tid < 144) {
        float b = 0.f;
        if (z == 0) {
            if (tid < 128)      b = mk_b1[tid];
            else if (tid < 130) b = fh_b1[tid - 128];
        } else if (tid < 128)   b = mk_b1[128 + tid];
        s_bias[tid] = b;
    }

    f32x4 acc[3][2];
#pragma unroll
    for (int g = 0; g < 3; ++g)
#pragma unroll
        for (int q = 0; q < 2; ++q) acc[g][q] = (f32x4){0.f, 0.f, 0.f, 0.f};

    for (int cc = 0; cc < 4; ++cc) {
        __syncthreads();
        for (int i = tid; i < 3 * 66 * 4; i += 512) {
            int r = i / 264;
            int rem = i - r * 264;
            int c = rem >> 2, un = rem & 3;
            int gy = h - 1 + r, gx = c - 1;
            u16x8 v = {0, 0, 0, 0, 0, 0, 0, 0};
            if ((unsigned)gy < 64u && (unsigned)gx < 64u)
                v = *(const u16x8*)&imgT[((size_t)((n * 64 + gy) * 64 + gx)) * 128 + cc * 32 + un * 8];
            *(u16x8*)&s_img[r][c][un * 8] = v;
        }
        __syncthreads();

        const unsigned short* wfp = w1f + (size_t)(z * 4 + cc) * 81 * 512 + lane * 8;
#pragma unroll
        for (int tap = 0; tap < 9; ++tap) {
            const int dy = tap / 3, dx = tap % 3;
            s16x8 bf[2];
#pragma unroll
            for (int q = 0; q < 2; ++q)
                bf[q] = *(const s16x8*)&s_img[dy][half * 32 + q * 16 + ln + dx][lg * 8];
#pragma unroll
            for (int gi = 0; gi < 3; ++gi) {
                if (gi < gn) {
                    s16x8 af = *(const s16x8*)&wfp[(size_t)(tap * 9 + g0 + gi) * 512];
#pragma unroll
                    for (int q = 0; q < 2; ++q)
                        acc[gi][q] = __builtin_amdgcn_mfma_f32_16x16x32_bf16(af, bf[q], acc[gi][q], 0, 0, 0);
                }
            }
        }
    }

    // epilogue: stores + per-channel partial stats
#pragma unroll
    for (int gi = 0; gi < 3; ++gi) {
        if (gi >= gn) continue;
        const int g = g0 + gi;
        float v[2][4];
#pragma unroll
        for (int q = 0; q < 2; ++q)
#pragma unroll
            for (int r = 0; r < 4; ++r)
                v[q][r] = acc[gi][q][r] + s_bias[g * 16 + lg * 4 + r];
        // stores
#pragma unroll
        for (int q = 0; q < 2; ++q) {
            const int px  = half * 32 + q * 16 + ln;
            const int pxg = h * 4 + half * 2 + q;
            if (z == 0 && g == 8) {
                if (lg == 0) {
#pragma unroll
                    for (int r = 0; r < 2; ++r)
                        h_pre[((size_t)(n * 2 + r)) * HWSZ + h * 64 + px] = v[q][r];
                }
            } else {
                u16x4 vv;
#pragma unroll
                for (int r = 0; r < 4; ++r) vv[r] = f2bf(v[q][r]);
                int ks  = z * 4 + (g >> 1);
                int lgp = ((g & 1) * 2 + (lg >> 1)) & 3;
                size_t off = ((((size_t)(n * 256 + pxg) * 8 + ks) * 4 + lgp) * 128) + ln * 8 + (lg & 1) * 4;
                *(u16x4*)&m_frag[off] = vv;
            }
        }
        // partial stats (sum over this wave's 32 px, then over 16 ln lanes)
#pragma unroll
        for (int r = 0; r < 4; ++r) {
            float s  = v[0][r] + v[1][r];
            float s2 = v[0][r] * v[0][r] + v[1][r] * v[1][r];
#pragma unroll
            for (int off = 1; off < 16; off <<= 1) {
                s  += __shfl_xor(s,  off, 64);
                s2 += __shfl_xor(s2, off, 64);
            }
            if (ln == 0) {
                s_ps[half][g * 16 + lg * 4 + r]  = s;
                s_ps2[half][g * 16 + lg * 4 + r] = s2;
            }
        }
    }
    __syncthreads();
    const int nch = z ? 128 : 130;
    if (tid < nch) {
        const int idx = z * 146 + tid;
        ps_s[(size_t)idx * 256 + hn]  = s_ps[0][tid] + s_ps[1][tid];
        ps_s2[(size_t)idx * 256 + hn] = s_ps2[0][tid] + s_ps2[1][tid];
    }
}

// ---------------------------------------------------------------------------
// K3: final BN stat reduction -> affine (a,b) for mask head (256 ch) and
// flow head (2 ch). One block, 288 active threads.
// ---------------------------------------------------------------------------
__global__ void __launch_bounds__(320)
bn_final2(const float* __restrict__ ps_s, const float* __restrict__ ps_s2,
          const float* __restrict__ mk_g, const float* __restrict__ mk_be,
          const float* __restrict__ fh_g, const float* __restrict__ fh_be,
          float* __restrict__ ab_m, float* __restrict__ ab_h)
{
    const int t = threadIdx.x;
    if (t >= 258) return;
    int idx;
    if (t < 256) idx = (t >> 7) * 146 + (t & 127);
    else         idx = 128 + (t - 256);
    float S = 0.f, S2 = 0.f;
    const float* p1 = ps_s  + (size_t)idx * 256;
    const float* p2 = ps_s2 + (size_t)idx * 256;
    for (int i = 0; i < 256; ++i) { S += p1[i]; S2 += p2[i]; }
    const float inv = 1.0f / (float)(N_B * HWSZ);
    float mu = S * inv;
    float var = S2 * inv - mu * mu;
    float r = rsqrtf(var + 1e-5f);
    if (t < 256) {
        float a = mk_g[t] * r;
        ab_m[2 * t] = a; ab_m[2 * t + 1] = mk_be[t] - mu * a;
    } else {
        int c = t - 256;
        float a = fh_g[c] * r;
        ab_h[2 * c] = a; ab_h[2 * c + 1] = fh_be[c] - mu * a;
    }
}

// ---------------------------------------------------------------------------
// K4: blocks 0..2047 in-place BN+ReLU on m_frag; blocks 2048..2175 flow conv2.
// ---------------------------------------------------------------------------
__global__ void __launch_bounds__(256)
bnrelu_flow(unsigned short* __restrict__ m_frag, const float* __restrict__ ab,
            const float* __restrict__ hpre, const float* __restrict__ ab_h,
            const float* __restrict__ w2, const float* __restrict__ b2,
            float* __restrict__ flow8)
{
    __shared__ float s_ab[512];
    const int t = threadIdx.x;
    if (blockIdx.x < 2048) {
        s_ab[t] = ab[t]; s_ab[256 + t] = ab[256 + t];
        __syncthreads();
        const unsigned u = blockIdx.x * 256 + t;
        const int lg = (u >> 4) & 3, ks = (u >> 7) & 7;
        const int cb = ks * 32 + lg * 8;
        u16x8 v = *(const u16x8*)&m_frag[(size_t)u * 8];
        u16x8 o;
#pragma unroll
        for (int j = 0; j < 8; ++j) {
            float a = s_ab[2 * (cb + j)], b = s_ab[2 * (cb + j) + 1];
            o[j] = f2bf(fmaxf(a * bf2f(v[j]) + b, 0.f));
        }
        *(u16x8*)&m_frag[(size_t)u * 8] = o;
        return;
    }
    int idx = (blockIdx.x - 2048) * 256 + t;
    int w = idx & 63, h = (idx >> 6) & 63, co = (idx >> 12) & 1, n = idx >> 13;
    float acc = b2[co];
#pragma unroll
    for (int ci = 0; ci < 2; ++ci) {
        float a = ab_h[2 * ci], b = ab_h[2 * ci + 1];
        const float* p = hpre + (size_t)(n * 2 + ci) * HWSZ;
        const float* wp = &w2[(co * 2 + ci) * 9];
#pragma unroll
        for (int dy = 0; dy < 3; ++dy)
#pragma unroll
            for (int dx = 0; dx < 3; ++dx) {
                int gy = h + dy - 1, gx = w + dx - 1;
                float v = 0.f;
                if ((unsigned)gy < 64u && (unsigned)gx < 64u)
                    v = fmaxf(a * p[gy * 64 + gx] + b, 0.f);
                acc += wp[dy * 3 + dx] * v;
            }
    }
    flow8[idx] = acc * 8.0f;
}

// ---------------------------------------------------------------------------
// K5: fused 1x1-conv GEMM + bias + softmax(9) + convex upsample.
// Grid 1024, id = hg + 16*uvt + 256*n  ->  id%8 = hg%8: image ROWS pin to
// XCDs (R2's accidental-optimal locality): per-XCD working set = 2hg m
// slices (512KB window) + all 16 w2f tiles (1.18MB) << 4MB L2.
// 512 thr, 77.5KB LDS -> 2 blocks/CU = 4 waves/SIMD.
// Output staged through dead s_w region -> fully linear 4KB-row stores
// (exact 32MB writes, no partial-line amplification).
// ---------------------------------------------------------------------------
__global__ void __launch_bounds__(512, 4)
mask_combine_mfma(const unsigned short* __restrict__ m_frag,
                  const unsigned short* __restrict__ w2f,
                  const float* __restrict__ mk_b2,
                  const float* __restrict__ flow8,
                  float* __restrict__ out)
{
    __shared__ unsigned short s_w[36864];       // 73,728 B fragment order
    __shared__ float s_fl[2][6][66];            // 3,168 B
    __shared__ float s_bias[9][16];             // 576 B

    const int id = blockIdx.x;
    const int hg = id & 15, uvt = (id >> 4) & 15, n = id >> 8;

    const int tid = threadIdx.x;
    const int wv = tid >> 6, lane = tid & 63;
    const int lg = lane >> 4, ln = lane & 15;
    const int r_l = wv >> 1, half = wv & 1;
    const int h = hg * 4 + r_l;

    {
        const u16x8* wsrc = (const u16x8*)(w2f + (size_t)uvt * 36864);
        u16x8* wdst = (u16x8*)s_w;
        for (int i = tid; i < 4608; i += 512) wdst[i] = wsrc[i];
    }
    for (int i = tid; i < 2 * 6 * 66; i += 512) {
        int c = i / 396, rem = i - c * 396, r = rem / 66, col = rem - r * 66;
        int gy = hg * 4 - 1 + r, gx = col - 1;
        float v = 0.f;
        if ((unsigned)gy < 64u && (unsigned)gx < 64u)
            v = flow8[((size_t)(n * 2 + c)) * HWSZ + gy * 64 + gx];
        s_fl[c][r][col] = v;
    }
    if (tid < 144) s_bias[tid >> 4][tid & 15] = 0.25f * mk_b2[(tid >> 4) * 256 + uvt * 16 + (tid & 15)];
    __syncthreads();

    const unsigned short* wk0 = s_w + lg * 128 + ln * 8;
    const unsigned short* mb = m_frag + (size_t)(n * 256 + h * 4 + half * 2) * 4096 + lg * 128 + ln * 8;

    f32x4 acc[9][2];
#pragma unroll
    for (int k = 0; k < 9; ++k)
#pragma unroll
        for (int q = 0; q < 2; ++q) acc[k][q] = (f32x4){0.f, 0.f, 0.f, 0.f};

    // rolling 4-deep B prefetch: 8 loads in flight before first MFMA
    s16x8 bq[4][2];
#pragma unroll
    for (int d = 0; d < 4; ++d)
#pragma unroll
        for (int q = 0; q < 2; ++q) bq[d][q] = *(const s16x8*)&mb[q * 4096 + d * 512];

#pragma unroll
    for (int ks = 0; ks < 8; ++ks) {
        const unsigned short* wk = wk0 + ks * 512;
#pragma unroll
        for (int k = 0; k < 9; ++k) {
            s16x8 af = *(const s16x8*)&wk[k * 4096];
#pragma unroll
            for (int q = 0; q < 2; ++q)
                acc[k][q] = __builtin_amdgcn_mfma_f32_16x16x32_bf16(af, bq[ks & 3][q], acc[k][q], 0, 0, 0);
        }
        if (ks < 4) {
#pragma unroll
            for (int q = 0; q < 2; ++q)
                bq[ks & 3][q] = *(const s16x8*)&mb[q * 4096 + (ks + 4) * 512];
        }
    }

    // all s_w reads complete -> reuse as fp32 output staging [c2][r_l4][1024]
    __syncthreads();
    float* s_o = (float*)s_w;

#pragma unroll
    for (int q = 0; q < 2; ++q) {
        const int w = half * 32 + q * 16 + ln;
        float o0[4], o1[4];
#pragma unroll
        for (int r = 0; r < 4; ++r) {
            const int vv = lg * 4 + r;
            float p[9], mx = -1e30f;
#pragma unroll
            for (int k = 0; k < 9; ++k) {
                p[k] = acc[k][q][r] + s_bias[k][vv];
                mx = fmaxf(mx, p[k]);
            }
            float sum = 0.f;
#pragma unroll
            for (int k = 0; k < 9; ++k) { p[k] = __expf(p[k] - mx); sum += p[k]; }
            float inv = 1.0f / sum;
            float a0 = 0.f, a1 = 0.f;
#pragma unroll
            for (int k = 0; k < 9; ++k) {
                const int dy = k / 3, dx = k % 3;
                a0 += p[k] * s_fl[0][r_l + dy][w + dx];
                a1 += p[k] * s_fl[1][r_l + dy][w + dx];
            }
            o0[r] = a0 * inv; o1[r] = a1 * inv;
        }
        *(f32x4*)&s_o[(0 * 4 + r_l) * 1024 + w * 16 + lg * 4] = (f32x4){o0[0], o0[1], o0[2], o0[3]};
        *(f32x4*)&s_o[(1 * 4 + r_l) * 1024 + w * 16 + lg * 4] = (f32x4){o1[0], o1[1], o1[2], o1[3]};
    }
    __syncthreads();

    // cooperative fully-linear store: 8 rows x 4KB
    {
        const int row = tid >> 6;            // 0..7: c = row>>2, r_l = row&3
        const int l64 = tid & 63;
        const int c = row >> 2, rl = row & 3;
        const float* srcp = &s_o[row * 1024 + l64 * 16];
        float* dstp = out + ((size_t)(n * 2 + c) * 1024 + (hg * 4 + rl) * 16 + uvt) * 1024 + l64 * 16;
#pragma unroll
        for (int j = 0; j < 4; ++j)
            *(f32x4*)&dstp[j * 4] = *(const f32x4*)&srcp[j * 4];
    }
}

// ---------------------------------------------------------------------------
extern "C" void kernel_launch(void* const* d_in, const int* in_sizes, int n_in,
                              void* d_out, int out_size, void* d_ws, size_t ws_size,
                              hipStream_t stream) {
    const float* img   = (const float*)d_in[0];
    const float* fh_w1 = (const float*)d_in[1];
    const float* fh_b1 = (const float*)d_in[2];
    const float* fh_g  = (const float*)d_in[3];
    const float* fh_be = (const float*)d_in[4];
    const float* fh_w2 = (const float*)d_in[5];
    const float* fh_b2 = (const float*)d_in[6];
    const float* mk_w1 = (const float*)d_in[7];
    const float* mk_b1 = (const float*)d_in[8];
    const float* mk_g  = (const float*)d_in[9];
    const float* mk_be = (const float*)d_in[10];
    const float* mk_w2 = (const float*)d_in[11];
    const float* mk_b2 = (const float*)d_in[12];
    float* out = (float*)d_out;

    char* p = (char*)d_ws;
    unsigned short* w2f    = (unsigned short*)p;  p += (size_t)1179648;
    unsigned short* w1f    = (unsigned short*)p;  p += (size_t)663552;
    unsigned short* imgT   = (unsigned short*)p;  p += (size_t)4194304;
    unsigned short* m_frag = (unsigned short*)p;  p += (size_t)8388608;
    float* h_pre  = (float*)p;  p += (size_t)131072;
    float* flow8  = (float*)p;  p += (size_t)131072;
    float* ps_s   = (float*)p;  p += (size_t)280576;
    float* ps_s2  = (float*)p;  p += (size_t)280576;
    float* ab_m   = (float*)p;  p += 2048;
    float* ab_h   = (float*)p;  p += 64;

    prep_all<<<2560, 256, 0, stream>>>(img, mk_w1, fh_w1, mk_w2, imgT, w1f, w2f);
    conv1_mfma<<<512, 512, 0, stream>>>(imgT, w1f, mk_b1, fh_b1, m_frag, h_pre, ps_s, ps_s2);
    bn_final2<<<1, 320, 0, stream>>>(ps_s, ps_s2, mk_g, mk_be, fh_g, fh_be, ab_m, ab_h);
    bnrelu_flow<<<2176, 256, 0, stream>>>(m_frag, ab_m, h_pre, ab_h, fh_w2, fh_b2, flow8);
    mask_combine_mfma<<<1024, 512, 0, stream>>>(m_frag, w2f, mk_b2, flow8, out);
}

// Round 8
// 108.608 us; speedup vs baseline: 1.0693x; 1.0693x over previous
//
#include <hip/hip_runtime.h>
#include <hip/hip_bf16.h>

#define N_B   4
#define C_IN  128
#define HWSZ  4096
#define C_M   256

typedef __attribute__((ext_vector_type(8))) short          s16x8;   // bf16x8 frag (4 VGPR)
typedef __attribute__((ext_vector_type(8))) unsigned short u16x8;
typedef __attribute__((ext_vector_type(4))) unsigned short u16x4;
typedef __attribute__((ext_vector_type(4))) float          f32x4;

__device__ __forceinline__ unsigned short f2bf(float f) {
    union { float f; unsigned u; } v; v.f = f;
    unsigned r = v.u + 0x7fffu + ((v.u >> 16) & 1u);   // RNE
    return (unsigned short)(r >> 16);
}
__device__ __forceinline__ float bf2f(unsigned short u) {
    union { unsigned u; float f; } v; v.u = ((unsigned)u) << 16; return v.f;
}

// ---------------------------------------------------------------------------
// K1: fused prep. Blocks 0..255: img transpose (n,ci,h,w)->bf16 (n,h,w,ci).
// Blocks 256..2559: fragment-ordered weights.
//  w1f[z2][cc4][tap9][g9][lane64][j8]; row=g*16+(lane&15), ci=cc*32+(lane>>4)*8+j
//  w2f[uvt16][k9][ks8][lg4][ln16][j8] = 0.25*mk_w2[(k*256+uvt*16+ln)*256+ks*32+lg*8+j]
// ---------------------------------------------------------------------------
__global__ void __launch_bounds__(256)
prep_all(const float* __restrict__ img,
         const float* __restrict__ mk_w1, const float* __restrict__ fh_w1,
         const float* __restrict__ mk_w2,
         unsigned short* __restrict__ imgT,
         unsigned short* __restrict__ w1f, unsigned short* __restrict__ w2f)
{
    __shared__ float s[128][65];
    const int b = blockIdx.x;
    if (b < 256) {
        const int n = b >> 6, h = b & 63;
        const float* src = img + (size_t)n * C_IN * HWSZ + h * 64;
        for (int i = threadIdx.x; i < 128 * 64; i += 256) {
            int ci = i >> 6, w = i & 63;
            s[ci][w] = src[(size_t)ci * HWSZ + w];
        }
        __syncthreads();
        unsigned short* dst = imgT + ((size_t)(n * 64 + h) * 64) * 128;
        for (int i = threadIdx.x; i < 64 * 128; i += 256) {
            int w = i >> 7, ci = i & 127;
            dst[(size_t)w * 128 + ci] = f2bf(s[ci][w]);
        }
        return;
    }
    int i = (b - 256) * 256 + threadIdx.x;
    if (i < 2304 * 256) {
        int uvt = i / 36864;
        int r   = i - uvt * 36864;
        int k   = r / 4096;
        int r2  = r - k * 4096;
        int ks  = r2 >> 9;
        int lg  = (r2 >> 7) & 3;
        int ln  = (r2 >> 3) & 15;
        int j   = r2 & 7;
        w2f[i] = f2bf(0.25f * mk_w2[(size_t)(k * 256 + uvt * 16 + ln) * 256 + ks * 32 + lg * 8 + j]);
    }
    if (i < 2 * 4 * 9 * 9 * 512) {
        int z   = i / 165888;
        int r   = i - z * 165888;
        int cc  = r / 41472;
        int r2  = r - cc * 41472;
        int tap = r2 / 4608;
        int r3  = r2 - tap * 4608;
        int g   = r3 / 512;
        int r4  = r3 - g * 512;
        int lane = r4 >> 3, j = r4 & 7;
        int lg = lane >> 4, ln = lane & 15;
        int row = g * 16 + ln;
        int ci  = cc * 32 + lg * 8 + j;
        float w = 0.f;
        if (z == 0) {
            if (row < 128)      w = mk_w1[((size_t)row * C_IN + ci) * 9 + tap];
            else if (row < 130) w = fh_w1[((size_t)(row - 128) * C_IN + ci) * 9 + tap];
        } else {
            if (row < 128)      w = mk_w1[((size_t)(128 + row) * C_IN + ci) * 9 + tap];
        }
        w1f[i] = f2bf(w);
    }
}

// ---------------------------------------------------------------------------
// K2: conv1 implicit-GEMM 3x3. Grid 512 (XCD-swizzled (n,h,z)), 512 thr,
// 2 blocks/CU -> 4 waves/SIMD. Wave = (gq4, half2): q=2 px-groups, 2-3 g.
// Also computes per-block BN channel partials (fp32, deterministic).
// m_frag unit: [n][pxg256][ks8][lg4][ln16][j8], c = ks*32+lg*8+j.
// ---------------------------------------------------------------------------
__global__ void __launch_bounds__(512, 4)
conv1_mfma(const unsigned short* __restrict__ imgT,
           const unsigned short* __restrict__ w1f,
           const float* __restrict__ mk_b1, const float* __restrict__ fh_b1,
           unsigned short* __restrict__ m_frag, float* __restrict__ h_pre,
           float* __restrict__ ps_s, float* __restrict__ ps_s2)
{
    __shared__ unsigned short s_img[3][66][40];   // 15,840 B
    __shared__ float s_bias[144];
    __shared__ float s_ps[2][144], s_ps2[2][144];

    const int hw = blockIdx.x;
    const int xcd = hw & 7, slot = hw >> 3;
    const int lid = xcd * 64 + slot;
    const int n = lid >> 7, h = (lid >> 1) & 63, z = lid & 1;
    const int hn = n * 64 + h;

    const int tid = threadIdx.x;
    const int wv = tid >> 6, lane = tid & 63;
    const int lg = lane >> 4, ln = lane & 15;
    const int gq = wv >> 1, half = wv & 1;
    const int g0 = z ? (gq * 2) : ((int[4]){0, 3, 5, 7})[gq];
    const int gn = z ? 2 : ((int[4]){3, 2, 2, 2})[gq];

    if (tid < 144) {
        float b = 0.f;
        if (z == 0) {
            if (tid < 128)      b = mk_b1[tid];
            else if (tid < 130) b = fh_b1[tid - 128];
        } else if (tid < 128)   b = mk_b1[128 + tid];
        s_bias[tid] = b;
    }

    f32x4 acc[3][2];
#pragma unroll
    for (int g = 0; g < 3; ++g)
#pragma unroll
        for (int q = 0; q < 2; ++q) acc[g][q] = (f32x4){0.f, 0.f, 0.f, 0.f};

    for (int cc = 0; cc < 4; ++cc) {
        __syncthreads();
        for (int i = tid; i < 3 * 66 * 4; i += 512) {
            int r = i / 264;
            int rem = i - r * 264;
            int c = rem >> 2, un = rem & 3;
            int gy = h - 1 + r, gx = c - 1;
            u16x8 v = {0, 0, 0, 0, 0, 0, 0, 0};
            if ((unsigned)gy < 64u && (unsigned)gx < 64u)
                v = *(const u16x8*)&imgT[((size_t)((n * 64 + gy) * 64 + gx)) * 128 + cc * 32 + un * 8];
            *(u16x8*)&s_img[r][c][un * 8] = v;
        }
        __syncthreads();

        const unsigned short* wfp = w1f + (size_t)(z * 4 + cc) * 81 * 512 + lane * 8;
#pragma unroll
        for (int tap = 0; tap < 9; ++tap) {
            const int dy = tap / 3, dx = tap % 3;
            s16x8 bf[2];
#pragma unroll
            for (int q = 0; q < 2; ++q)
                bf[q] = *(const s16x8*)&s_img[dy][half * 32 + q * 16 + ln + dx][lg * 8];
#pragma unroll
            for (int gi = 0; gi < 3; ++gi) {
                if (gi < gn) {
                    s16x8 af = *(const s16x8*)&wfp[(size_t)(tap * 9 + g0 + gi) * 512];
#pragma unroll
                    for (int q = 0; q < 2; ++q)
                        acc[gi][q] = __builtin_amdgcn_mfma_f32_16x16x32_bf16(af, bf[q], acc[gi][q], 0, 0, 0);
                }
            }
        }
    }

    // epilogue: stores + per-channel partial stats
#pragma unroll
    for (int gi = 0; gi < 3; ++gi) {
        if (gi >= gn) continue;
        const int g = g0 + gi;
        float v[2][4];
#pragma unroll
        for (int q = 0; q < 2; ++q)
#pragma unroll
            for (int r = 0; r < 4; ++r)
                v[q][r] = acc[gi][q][r] + s_bias[g * 16 + lg * 4 + r];
        // stores
#pragma unroll
        for (int q = 0; q < 2; ++q) {
            const int px  = half * 32 + q * 16 + ln;
            const int pxg = h * 4 + half * 2 + q;
            if (z == 0 && g == 8) {
                if (lg == 0) {
#pragma unroll
                    for (int r = 0; r < 2; ++r)
                        h_pre[((size_t)(n * 2 + r)) * HWSZ + h * 64 + px] = v[q][r];
                }
            } else {
                u16x4 vv;
#pragma unroll
                for (int r = 0; r < 4; ++r) vv[r] = f2bf(v[q][r]);
                int ks  = z * 4 + (g >> 1);
                int lgp = ((g & 1) * 2 + (lg >> 1)) & 3;
                size_t off = ((((size_t)(n * 256 + pxg) * 8 + ks) * 4 + lgp) * 128) + ln * 8 + (lg & 1) * 4;
                *(u16x4*)&m_frag[off] = vv;
            }
        }
        // partial stats (sum over this wave's 32 px, then over 16 ln lanes)
#pragma unroll
        for (int r = 0; r < 4; ++r) {
            float s  = v[0][r] + v[1][r];
            float s2 = v[0][r] * v[0][r] + v[1][r] * v[1][r];
#pragma unroll
            for (int off = 1; off < 16; off <<= 1) {
                s  += __shfl_xor(s,  off, 64);
                s2 += __shfl_xor(s2, off, 64);
            }
            if (ln == 0) {
                s_ps[half][g * 16 + lg * 4 + r]  = s;
                s_ps2[half][g * 16 + lg * 4 + r] = s2;
            }
        }
    }
    __syncthreads();
    const int nch = z ? 128 : 130;
    if (tid < nch) {
        const int idx = z * 146 + tid;
        ps_s[(size_t)idx * 256 + hn]  = s_ps[0][tid] + s_ps[1][tid];
        ps_s2[(size_t)idx * 256 + hn] = s_ps2[0][tid] + s_ps2[1][tid];
    }
}

// ---------------------------------------------------------------------------
// K3: final BN stat reduction -> affine (a,b) for mask head (256 ch) and
// flow head (2 ch). One block, 288 active threads.
// ---------------------------------------------------------------------------
__global__ void __launch_bounds__(320)
bn_final2(const float* __restrict__ ps_s, const float* __restrict__ ps_s2,
          const float* __restrict__ mk_g, const float* __restrict__ mk_be,
          const float* __restrict__ fh_g, const float* __restrict__ fh_be,
          float* __restrict__ ab_m, float* __restrict__ ab_h)
{
    const int t = threadIdx.x;
    if (t >= 258) return;
    int idx;
    if (t < 256) idx = (t >> 7) * 146 + (t & 127);
    else         idx = 128 + (t - 256);
    float S = 0.f, S2 = 0.f;
    const float* p1 = ps_s  + (size_t)idx * 256;
    const float* p2 = ps_s2 + (size_t)idx * 256;
    for (int i = 0; i < 256; ++i) { S += p1[i]; S2 += p2[i]; }
    const float inv = 1.0f / (float)(N_B * HWSZ);
    float mu = S * inv;
    float var = S2 * inv - mu * mu;
    float r = rsqrtf(var + 1e-5f);
    if (t < 256) {
        float a = mk_g[t] * r;
        ab_m[2 * t] = a; ab_m[2 * t + 1] = mk_be[t] - mu * a;
    } else {
        int c = t - 256;
        float a = fh_g[c] * r;
        ab_h[2 * c] = a; ab_h[2 * c + 1] = fh_be[c] - mu * a;
    }
}

// ---------------------------------------------------------------------------
// K4: blocks 0..2047 in-place BN+ReLU on m_frag; blocks 2048..2175 flow conv2.
// ---------------------------------------------------------------------------
__global__ void __launch_bounds__(256)
bnrelu_flow(unsigned short* __restrict__ m_frag, const float* __restrict__ ab,
            const float* __restrict__ hpre, const float* __restrict__ ab_h,
            const float* __restrict__ w2, const float* __restrict__ b2,
            float* __restrict__ flow8)
{
    __shared__ float s_ab[512];
    const int t = threadIdx.x;
    if (blockIdx.x < 2048) {
        s_ab[t] = ab[t]; s_ab[256 + t] = ab[256 + t];
        __syncthreads();
        const unsigned u = blockIdx.x * 256 + t;
        const int lg = (u >> 4) & 3, ks = (u >> 7) & 7;
        const int cb = ks * 32 + lg * 8;
        u16x8 v = *(const u16x8*)&m_frag[(size_t)u * 8];
        u16x8 o;
#pragma unroll
        for (int j = 0; j < 8; ++j) {
            float a = s_ab[2 * (cb + j)], b = s_ab[2 * (cb + j) + 1];
            o[j] = f2bf(fmaxf(a * bf2f(v[j]) + b, 0.f));
        }
        *(u16x8*)&m_frag[(size_t)u * 8] = o;
        return;
    }
    int idx = (blockIdx.x - 2048) * 256 + t;
    int w = idx & 63, h = (idx >> 6) & 63, co = (idx >> 12) & 1, n = idx >> 13;
    float acc = b2[co];
#pragma unroll
    for (int ci = 0; ci < 2; ++ci) {
        float a = ab_h[2 * ci], b = ab_h[2 * ci + 1];
        const float* p = hpre + (size_t)(n * 2 + ci) * HWSZ;
        const float* wp = &w2[(co * 2 + ci) * 9];
#pragma unroll
        for (int dy = 0; dy < 3; ++dy)
#pragma unroll
            for (int dx = 0; dx < 3; ++dx) {
                int gy = h + dy - 1, gx = w + dx - 1;
                float v = 0.f;
                if ((unsigned)gy < 64u && (unsigned)gx < 64u)
                    v = fmaxf(a * p[gy * 64 + gx] + b, 0.f);
                acc += wp[dy * 3 + dx] * v;
            }
    }
    flow8[idx] = acc * 8.0f;
}

// ---------------------------------------------------------------------------
// K5: fused 1x1-conv GEMM + bias + softmax(9) + convex upsample.
// Grid 1024, id = hg + 16*uvt + 256*n -> id%8 = hg%8 (rows pin to XCDs).
// 512 thr, 77.5KB LDS -> 2 blocks/CU = 4 waves/SIMD.
// R8: output staged in dead s_w, then stored with LANE-CONTIGUOUS float4s
// (each instruction covers 1KB fully -> no L2 write-allocate fetches).
// ---------------------------------------------------------------------------
__global__ void __launch_bounds__(512, 4)
mask_combine_mfma(const unsigned short* __restrict__ m_frag,
                  const unsigned short* __restrict__ w2f,
                  const float* __restrict__ mk_b2,
                  const float* __restrict__ flow8,
                  float* __restrict__ out)
{
    __shared__ unsigned short s_w[36864];       // 73,728 B fragment order
    __shared__ float s_fl[2][6][66];            // 3,168 B
    __shared__ float s_bias[9][16];             // 576 B

    const int id = blockIdx.x;
    const int hg = id & 15, uvt = (id >> 4) & 15, n = id >> 8;

    const int tid = threadIdx.x;
    const int wv = tid >> 6, lane = tid & 63;
    const int lg = lane >> 4, ln = lane & 15;
    const int r_l = wv >> 1, half = wv & 1;
    const int h = hg * 4 + r_l;

    {
        const u16x8* wsrc = (const u16x8*)(w2f + (size_t)uvt * 36864);
        u16x8* wdst = (u16x8*)s_w;
        for (int i = tid; i < 4608; i += 512) wdst[i] = wsrc[i];
    }
    for (int i = tid; i < 2 * 6 * 66; i += 512) {
        int c = i / 396, rem = i - c * 396, r = rem / 66, col = rem - r * 66;
        int gy = hg * 4 - 1 + r, gx = col - 1;
        float v = 0.f;
        if ((unsigned)gy < 64u && (unsigned)gx < 64u)
            v = flow8[((size_t)(n * 2 + c)) * HWSZ + gy * 64 + gx];
        s_fl[c][r][col] = v;
    }
    if (tid < 144) s_bias[tid >> 4][tid & 15] = 0.25f * mk_b2[(tid >> 4) * 256 + uvt * 16 + (tid & 15)];
    __syncthreads();

    const unsigned short* wk0 = s_w + lg * 128 + ln * 8;
    const unsigned short* mb = m_frag + (size_t)(n * 256 + h * 4 + half * 2) * 4096 + lg * 128 + ln * 8;

    f32x4 acc[9][2];
#pragma unroll
    for (int k = 0; k < 9; ++k)
#pragma unroll
        for (int q = 0; q < 2; ++q) acc[k][q] = (f32x4){0.f, 0.f, 0.f, 0.f};

    // rolling 4-deep B prefetch: 8 loads in flight before first MFMA
    s16x8 bq[4][2];
#pragma unroll
    for (int d = 0; d < 4; ++d)
#pragma unroll
        for (int q = 0; q < 2; ++q) bq[d][q] = *(const s16x8*)&mb[q * 4096 + d * 512];

#pragma unroll
    for (int ks = 0; ks < 8; ++ks) {
        const unsigned short* wk = wk0 + ks * 512;
#pragma unroll
        for (int k = 0; k < 9; ++k) {
            s16x8 af = *(const s16x8*)&wk[k * 4096];
#pragma unroll
            for (int q = 0; q < 2; ++q)
                acc[k][q] = __builtin_amdgcn_mfma_f32_16x16x32_bf16(af, bq[ks & 3][q], acc[k][q], 0, 0, 0);
        }
        if (ks < 4) {
#pragma unroll
            for (int q = 0; q < 2; ++q)
                bq[ks & 3][q] = *(const s16x8*)&mb[q * 4096 + (ks + 4) * 512];
        }
    }

    // all s_w reads complete -> reuse as fp32 output staging [c2][r_l4][1024]
    __syncthreads();
    float* s_o = (float*)s_w;

#pragma unroll
    for (int q = 0; q < 2; ++q) {
        const int w = half * 32 + q * 16 + ln;
        float o0[4], o1[4];
#pragma unroll
        for (int r = 0; r < 4; ++r) {
            const int vv = lg * 4 + r;
            float p[9], mx = -1e30f;
#pragma unroll
            for (int k = 0; k < 9; ++k) {
                p[k] = acc[k][q][r] + s_bias[k][vv];
                mx = fmaxf(mx, p[k]);
            }
            float sum = 0.f;
#pragma unroll
            for (int k = 0; k < 9; ++k) { p[k] = __expf(p[k] - mx); sum += p[k]; }
            float inv = 1.0f / sum;
            float a0 = 0.f, a1 = 0.f;
#pragma unroll
            for (int k = 0; k < 9; ++k) {
                const int dy = k / 3, dx = k % 3;
                a0 += p[k] * s_fl[0][r_l + dy][w + dx];
                a1 += p[k] * s_fl[1][r_l + dy][w + dx];
            }
            o0[r] = a0 * inv; o1[r] = a1 * inv;
        }
        *(f32x4*)&s_o[(0 * 4 + r_l) * 1024 + w * 16 + lg * 4] = (f32x4){o0[0], o0[1], o0[2], o0[3]};
        *(f32x4*)&s_o[(1 * 4 + r_l) * 1024 + w * 16 + lg * 4] = (f32x4){o1[0], o1[1], o1[2], o1[3]};
    }
    __syncthreads();

    // cooperative LANE-CONTIGUOUS store: consecutive lanes -> consecutive
    // float4s; each wave instruction covers 1KB of fully-written lines.
    for (int i = tid; i < 2048; i += 512) {
        const int idx = i * 4;           // flat float index into s_o
        const int row = idx >> 10;       // 0..7: c = row>>2, rl = row&3
        const int col = idx & 1023;
        const int c = row >> 2, rl = row & 3;
        f32x4 v = *(const f32x4*)&s_o[idx];
        *(f32x4*)(out + ((size_t)(n * 2 + c) * 1024 + (hg * 4 + rl) * 16 + uvt) * 1024 + col) = v;
    }
}

// ---------------------------------------------------------------------------
extern "C" void kernel_launch(void* const* d_in, const int* in_sizes, int n_in,
                              void* d_out, int out_size, void* d_ws, size_t ws_size,
                              hipStream_t stream) {
    const float* img   = (const float*)d_in[0];
    const float* fh_w1 = (const float*)d_in[1];
    const float* fh_b1 = (const float*)d_in[2];
    const float* fh_g  = (const float*)d_in[3];
    const float* fh_be = (const float*)d_in[4];
    const float* fh_w2 = (const float*)d_in[5];
    const float* fh_b2 = (const float*)d_in[6];
    const float* mk_w1 = (const float*)d_in[7];
    const float* mk_b1 = (const float*)d_in[8];
    const float* mk_g  = (const float*)d_in[9];
    const float* mk_be = (const float*)d_in[10];
    const float* mk_w2 = (const float*)d_in[11];
    const float* mk_b2 = (const float*)d_in[12];
    float* out = (float*)d_out;

    char* p = (char*)d_ws;
    unsigned short* w2f    = (unsigned short*)p;  p += (size_t)1179648;
    unsigned short* w1f    = (unsigned short*)p;  p += (size_t)663552;
    unsigned short* imgT   = (unsigned short*)p;  p += (size_t)4194304;
    unsigned short* m_frag = (unsigned short*)p;  p += (size_t)8388608;
    float* h_pre  = (float*)p;  p += (size_t)131072;
    float* flow8  = (float*)p;  p += (size_t)131072;
    float* ps_s   = (float*)p;  p += (size_t)280576;
    float* ps_s2  = (float*)p;  p += (size_t)280576;
    float* ab_m   = (float*)p;  p += 2048;
    float* ab_h   = (float*)p;  p += 64;

    prep_all<<<2560, 256, 0, stream>>>(img, mk_w1, fh_w1, mk_w2, imgT, w1f, w2f);
    conv1_mfma<<<512, 512, 0, stream>>>(imgT, w1f, mk_b1, fh_b1, m_frag, h_pre, ps_s, ps_s2);
    bn_final2<<<1, 320, 0, stream>>>(ps_s, ps_s2, mk_g, mk_be, fh_g, fh_be, ab_m, ab_h);
    bnrelu_flow<<<2176, 256, 0, stream>>>(m_frag, ab_m, h_pre, ab_h, fh_w2, fh_b2, flow8);
    mask_combine_mfma<<<1024, 512, 0, stream>>>(m_frag, w2f, mk_b2, flow8, out);
}

// Round 9
// 105.793 us; speedup vs baseline: 1.0977x; 1.0266x over previous
//
#include <hip/hip_runtime.h>
#include <hip/hip_bf16.h>

#define N_B   4
#define C_IN  128
#define HWSZ  4096
#define C_M   256

typedef __attribute__((ext_vector_type(8))) short          s16x8;   // bf16x8 frag (4 VGPR)
typedef __attribute__((ext_vector_type(8))) unsigned short u16x8;
typedef __attribute__((ext_vector_type(4))) unsigned short u16x4;
typedef __attribute__((ext_vector_type(4))) float          f32x4;

__device__ __forceinline__ unsigned short f2bf(float f) {
    union { float f; unsigned u; } v; v.f = f;
    unsigned r = v.u + 0x7fffu + ((v.u >> 16) & 1u);   // RNE
    return (unsigned short)(r >> 16);
}
__device__ __forceinline__ float bf2f(unsigned short u) {
    union { unsigned u; float f; } v; v.u = ((unsigned)u) << 16; return v.f;
}

// ---------------------------------------------------------------------------
// K1: fused prep. Blocks 0..255: img transpose (n,ci,h,w)->bf16 (n,h,w,ci).
// Blocks 256..2559: fragment-ordered weights.
//  w1f[z2][cc4][tap9][g9][lane64][j8]; row=g*16+(lane&15), ci=cc*32+(lane>>4)*8+j
//  w2f[uvt16][k9][ks8][lg4][ln16][j8] = 0.25*mk_w2[(k*256+uvt*16+ln)*256+ks*32+lg*8+j]
// ---------------------------------------------------------------------------
__global__ void __launch_bounds__(256)
prep_all(const float* __restrict__ img,
         const float* __restrict__ mk_w1, const float* __restrict__ fh_w1,
         const float* __restrict__ mk_w2,
         unsigned short* __restrict__ imgT,
         unsigned short* __restrict__ w1f, unsigned short* __restrict__ w2f)
{
    __shared__ float s[128][65];
    const int b = blockIdx.x;
    if (b < 256) {
        const int n = b >> 6, h = b & 63;
        const float* src = img + (size_t)n * C_IN * HWSZ + h * 64;
        for (int i = threadIdx.x; i < 128 * 64; i += 256) {
            int ci = i >> 6, w = i & 63;
            s[ci][w] = src[(size_t)ci * HWSZ + w];
        }
        __syncthreads();
        unsigned short* dst = imgT + ((size_t)(n * 64 + h) * 64) * 128;
        for (int i = threadIdx.x; i < 64 * 128; i += 256) {
            int w = i >> 7, ci = i & 127;
            dst[(size_t)w * 128 + ci] = f2bf(s[ci][w]);
        }
        return;
    }
    int i = (b - 256) * 256 + threadIdx.x;
    if (i < 2304 * 256) {
        int uvt = i / 36864;
        int r   = i - uvt * 36864;
        int k   = r / 4096;
        int r2  = r - k * 4096;
        int ks  = r2 >> 9;
        int lg  = (r2 >> 7) & 3;
        int ln  = (r2 >> 3) & 15;
        int j   = r2 & 7;
        w2f[i] = f2bf(0.25f * mk_w2[(size_t)(k * 256 + uvt * 16 + ln) * 256 + ks * 32 + lg * 8 + j]);
    }
    if (i < 2 * 4 * 9 * 9 * 512) {
        int z   = i / 165888;
        int r   = i - z * 165888;
        int cc  = r / 41472;
        int r2  = r - cc * 41472;
        int tap = r2 / 4608;
        int r3  = r2 - tap * 4608;
        int g   = r3 / 512;
        int r4  = r3 - g * 512;
        int lane = r4 >> 3, j = r4 & 7;
        int lg = lane >> 4, ln = lane & 15;
        int row = g * 16 + ln;
        int ci  = cc * 32 + lg * 8 + j;
        float w = 0.f;
        if (z == 0) {
            if (row < 128)      w = mk_w1[((size_t)row * C_IN + ci) * 9 + tap];
            else if (row < 130) w = fh_w1[((size_t)(row - 128) * C_IN + ci) * 9 + tap];
        } else {
            if (row < 128)      w = mk_w1[((size_t)(128 + row) * C_IN + ci) * 9 + tap];
        }
        w1f[i] = f2bf(w);
    }
}

// ---------------------------------------------------------------------------
// K2: conv1 implicit-GEMM 3x3. Grid 512 (XCD-swizzled (n,h,z)), 512 thr,
// 2 blocks/CU -> 4 waves/SIMD. Wave = (gq4, half2): q=2 px-groups, 2-3 g.
// Regs: 96 VGPR + 24 AGPR = 120 <= 128 cap -> no spill.
// m_frag unit: [n][pxg256][ks8][lg4][ln16][j8], c = ks*32+lg*8+j.
// ---------------------------------------------------------------------------
__global__ void __launch_bounds__(512, 4)
conv1_mfma(const unsigned short* __restrict__ imgT,
           const unsigned short* __restrict__ w1f,
           const float* __restrict__ mk_b1, const float* __restrict__ fh_b1,
           unsigned short* __restrict__ m_frag, float* __restrict__ h_pre,
           float* __restrict__ ps_s, float* __restrict__ ps_s2)
{
    __shared__ unsigned short s_img[3][66][40];   // 15,840 B
    __shared__ float s_bias[144];
    __shared__ float s_ps[2][144], s_ps2[2][144];

    const int hw = blockIdx.x;
    const int xcd = hw & 7, slot = hw >> 3;
    const int lid = xcd * 64 + slot;
    const int n = lid >> 7, h = (lid >> 1) & 63, z = lid & 1;
    const int hn = n * 64 + h;

    const int tid = threadIdx.x;
    const int wv = tid >> 6, lane = tid & 63;
    const int lg = lane >> 4, ln = lane & 15;
    const int gq = wv >> 1, half = wv & 1;
    const int g0 = z ? (gq * 2) : ((int[4]){0, 3, 5, 7})[gq];
    const int gn = z ? 2 : ((int[4]){3, 2, 2, 2})[gq];

    if (tid < 144) {
        float b = 0.f;
        if (z == 0) {
            if (tid < 128)      b = mk_b1[tid];
            else if (tid < 130) b = fh_b1[tid - 128];
        } else if (tid < 128)   b = mk_b1[128 + tid];
        s_bias[tid] = b;
    }

    f32x4 acc[3][2];
#pragma unroll
    for (int g = 0; g < 3; ++g)
#pragma unroll
        for (int q = 0; q < 2; ++q) acc[g][q] = (f32x4){0.f, 0.f, 0.f, 0.f};

    for (int cc = 0; cc < 4; ++cc) {
        __syncthreads();
        for (int i = tid; i < 3 * 66 * 4; i += 512) {
            int r = i / 264;
            int rem = i - r * 264;
            int c = rem >> 2, un = rem & 3;
            int gy = h - 1 + r, gx = c - 1;
            u16x8 v = {0, 0, 0, 0, 0, 0, 0, 0};
            if ((unsigned)gy < 64u && (unsigned)gx < 64u)
                v = *(const u16x8*)&imgT[((size_t)((n * 64 + gy) * 64 + gx)) * 128 + cc * 32 + un * 8];
            *(u16x8*)&s_img[r][c][un * 8] = v;
        }
        __syncthreads();

        const unsigned short* wfp = w1f + (size_t)(z * 4 + cc) * 81 * 512 + lane * 8;
#pragma unroll
        for (int tap = 0; tap < 9; ++tap) {
            const int dy = tap / 3, dx = tap % 3;
            s16x8 bf[2];
#pragma unroll
            for (int q = 0; q < 2; ++q)
                bf[q] = *(const s16x8*)&s_img[dy][half * 32 + q * 16 + ln + dx][lg * 8];
#pragma unroll
            for (int gi = 0; gi < 3; ++gi) {
                if (gi < gn) {
                    s16x8 af = *(const s16x8*)&wfp[(size_t)(tap * 9 + g0 + gi) * 512];
#pragma unroll
                    for (int q = 0; q < 2; ++q)
                        acc[gi][q] = __builtin_amdgcn_mfma_f32_16x16x32_bf16(af, bf[q], acc[gi][q], 0, 0, 0);
                }
            }
        }
    }

    // epilogue: stores + per-channel partial stats
#pragma unroll
    for (int gi = 0; gi < 3; ++gi) {
        if (gi >= gn) continue;
        const int g = g0 + gi;
        float v[2][4];
#pragma unroll
        for (int q = 0; q < 2; ++q)
#pragma unroll
            for (int r = 0; r < 4; ++r)
                v[q][r] = acc[gi][q][r] + s_bias[g * 16 + lg * 4 + r];
        // stores
#pragma unroll
        for (int q = 0; q < 2; ++q) {
            const int px  = half * 32 + q * 16 + ln;
            const int pxg = h * 4 + half * 2 + q;
            if (z == 0 && g == 8) {
                if (lg == 0) {
#pragma unroll
                    for (int r = 0; r < 2; ++r)
                        h_pre[((size_t)(n * 2 + r)) * HWSZ + h * 64 + px] = v[q][r];
                }
            } else {
                u16x4 vv;
#pragma unroll
                for (int r = 0; r < 4; ++r) vv[r] = f2bf(v[q][r]);
                int ks  = z * 4 + (g >> 1);
                int lgp = ((g & 1) * 2 + (lg >> 1)) & 3;
                size_t off = ((((size_t)(n * 256 + pxg) * 8 + ks) * 4 + lgp) * 128) + ln * 8 + (lg & 1) * 4;
                *(u16x4*)&m_frag[off] = vv;
            }
        }
        // partial stats (sum over this wave's 32 px, then over 16 ln lanes)
#pragma unroll
        for (int r = 0; r < 4; ++r) {
            float s  = v[0][r] + v[1][r];
            float s2 = v[0][r] * v[0][r] + v[1][r] * v[1][r];
#pragma unroll
            for (int off = 1; off < 16; off <<= 1) {
                s  += __shfl_xor(s,  off, 64);
                s2 += __shfl_xor(s2, off, 64);
            }
            if (ln == 0) {
                s_ps[half][g * 16 + lg * 4 + r]  = s;
                s_ps2[half][g * 16 + lg * 4 + r] = s2;
            }
        }
    }
    __syncthreads();
    const int nch = z ? 128 : 130;
    if (tid < nch) {
        const int idx = z * 146 + tid;
        ps_s[(size_t)idx * 256 + hn]  = s_ps[0][tid] + s_ps[1][tid];
        ps_s2[(size_t)idx * 256 + hn] = s_ps2[0][tid] + s_ps2[1][tid];
    }
}

// ---------------------------------------------------------------------------
// K3: final BN stat reduction -> affine (a,b) for mask head (256 ch) and
// flow head (2 ch). One block, 288 active threads.
// ---------------------------------------------------------------------------
__global__ void __launch_bounds__(320)
bn_final2(const float* __restrict__ ps_s, const float* __restrict__ ps_s2,
          const float* __restrict__ mk_g, const float* __restrict__ mk_be,
          const float* __restrict__ fh_g, const float* __restrict__ fh_be,
          float* __restrict__ ab_m, float* __restrict__ ab_h)
{
    const int t = threadIdx.x;
    if (t >= 258) return;
    int idx;
    if (t < 256) idx = (t >> 7) * 146 + (t & 127);
    else         idx = 128 + (t - 256);
    float S = 0.f, S2 = 0.f;
    const float* p1 = ps_s  + (size_t)idx * 256;
    const float* p2 = ps_s2 + (size_t)idx * 256;
    for (int i = 0; i < 256; ++i) { S += p1[i]; S2 += p2[i]; }
    const float inv = 1.0f / (float)(N_B * HWSZ);
    float mu = S * inv;
    float var = S2 * inv - mu * mu;
    float r = rsqrtf(var + 1e-5f);
    if (t < 256) {
        float a = mk_g[t] * r;
        ab_m[2 * t] = a; ab_m[2 * t + 1] = mk_be[t] - mu * a;
    } else {
        int c = t - 256;
        float a = fh_g[c] * r;
        ab_h[2 * c] = a; ab_h[2 * c + 1] = fh_be[c] - mu * a;
    }
}

// ---------------------------------------------------------------------------
// K4: blocks 0..2047 in-place BN+ReLU on m_frag; blocks 2048..2175 flow conv2.
// ---------------------------------------------------------------------------
__global__ void __launch_bounds__(256)
bnrelu_flow(unsigned short* __restrict__ m_frag, const float* __restrict__ ab,
            const float* __restrict__ hpre, const float* __restrict__ ab_h,
            const float* __restrict__ w2, const float* __restrict__ b2,
            float* __restrict__ flow8)
{
    __shared__ float s_ab[512];
    const int t = threadIdx.x;
    if (blockIdx.x < 2048) {
        s_ab[t] = ab[t]; s_ab[256 + t] = ab[256 + t];
        __syncthreads();
        const unsigned u = blockIdx.x * 256 + t;
        const int lg = (u >> 4) & 3, ks = (u >> 7) & 7;
        const int cb = ks * 32 + lg * 8;
        u16x8 v = *(const u16x8*)&m_frag[(size_t)u * 8];
        u16x8 o;
#pragma unroll
        for (int j = 0; j < 8; ++j) {
            float a = s_ab[2 * (cb + j)], b = s_ab[2 * (cb + j) + 1];
            o[j] = f2bf(fmaxf(a * bf2f(v[j]) + b, 0.f));
        }
        *(u16x8*)&m_frag[(size_t)u * 8] = o;
        return;
    }
    int idx = (blockIdx.x - 2048) * 256 + t;
    int w = idx & 63, h = (idx >> 6) & 63, co = (idx >> 12) & 1, n = idx >> 13;
    float acc = b2[co];
#pragma unroll
    for (int ci = 0; ci < 2; ++ci) {
        float a = ab_h[2 * ci], b = ab_h[2 * ci + 1];
        const float* p = hpre + (size_t)(n * 2 + ci) * HWSZ;
        const float* wp = &w2[(co * 2 + ci) * 9];
#pragma unroll
        for (int dy = 0; dy < 3; ++dy)
#pragma unroll
            for (int dx = 0; dx < 3; ++dx) {
                int gy = h + dy - 1, gx = w + dx - 1;
                float v = 0.f;
                if ((unsigned)gy < 64u && (unsigned)gx < 64u)
                    v = fmaxf(a * p[gy * 64 + gx] + b, 0.f);
                acc += wp[dy * 3 + dx] * v;
            }
    }
    flow8[idx] = acc * 8.0f;
}

// ---------------------------------------------------------------------------
// K5: fused 1x1-conv GEMM + bias + softmax(9) + convex upsample.
// Grid 1024, id = hg + 16*uvt + 256*n -> id%8 = hg%8 (rows pin to XCDs).
// 512 thr, 77.5KB LDS -> 2 blocks/CU.
// R9: __launch_bounds__(512, 3) -> 170-reg cap. acc(72 AGPR) + bq(32 VGPR)
// + temps now FIT -> no scratch spill (R5-R8 spilled ~70MB/dispatch under
// the 128-reg cap of (512,4); dur was pure spill-traffic-bound).
// ---------------------------------------------------------------------------
__global__ void __launch_bounds__(512, 3)
mask_combine_mfma(const unsigned short* __restrict__ m_frag,
                  const unsigned short* __restrict__ w2f,
                  const float* __restrict__ mk_b2,
                  const float* __restrict__ flow8,
                  float* __restrict__ out)
{
    __shared__ unsigned short s_w[36864];       // 73,728 B fragment order
    __shared__ float s_fl[2][6][66];            // 3,168 B
    __shared__ float s_bias[9][16];             // 576 B

    const int id = blockIdx.x;
    const int hg = id & 15, uvt = (id >> 4) & 15, n = id >> 8;

    const int tid = threadIdx.x;
    const int wv = tid >> 6, lane = tid & 63;
    const int lg = lane >> 4, ln = lane & 15;
    const int r_l = wv >> 1, half = wv & 1;
    const int h = hg * 4 + r_l;

    {
        const u16x8* wsrc = (const u16x8*)(w2f + (size_t)uvt * 36864);
        u16x8* wdst = (u16x8*)s_w;
        for (int i = tid; i < 4608; i += 512) wdst[i] = wsrc[i];
    }
    for (int i = tid; i < 2 * 6 * 66; i += 512) {
        int c = i / 396, rem = i - c * 396, r = rem / 66, col = rem - r * 66;
        int gy = hg * 4 - 1 + r, gx = col - 1;
        float v = 0.f;
        if ((unsigned)gy < 64u && (unsigned)gx < 64u)
            v = flow8[((size_t)(n * 2 + c)) * HWSZ + gy * 64 + gx];
        s_fl[c][r][col] = v;
    }
    if (tid < 144) s_bias[tid >> 4][tid & 15] = 0.25f * mk_b2[(tid >> 4) * 256 + uvt * 16 + (tid & 15)];
    __syncthreads();

    const unsigned short* wk0 = s_w + lg * 128 + ln * 8;
    const unsigned short* mb = m_frag + (size_t)(n * 256 + h * 4 + half * 2) * 4096 + lg * 128 + ln * 8;

    f32x4 acc[9][2];
#pragma unroll
    for (int k = 0; k < 9; ++k)
#pragma unroll
        for (int q = 0; q < 2; ++q) acc[k][q] = (f32x4){0.f, 0.f, 0.f, 0.f};

    // rolling 4-deep B prefetch: 8 loads in flight before first MFMA
    s16x8 bq[4][2];
#pragma unroll
    for (int d = 0; d < 4; ++d)
#pragma unroll
        for (int q = 0; q < 2; ++q) bq[d][q] = *(const s16x8*)&mb[q * 4096 + d * 512];

#pragma unroll
    for (int ks = 0; ks < 8; ++ks) {
        const unsigned short* wk = wk0 + ks * 512;
#pragma unroll
        for (int k = 0; k < 9; ++k) {
            s16x8 af = *(const s16x8*)&wk[k * 4096];
#pragma unroll
            for (int q = 0; q < 2; ++q)
                acc[k][q] = __builtin_amdgcn_mfma_f32_16x16x32_bf16(af, bq[ks & 3][q], acc[k][q], 0, 0, 0);
        }
        if (ks < 4) {
#pragma unroll
            for (int q = 0; q < 2; ++q)
                bq[ks & 3][q] = *(const s16x8*)&mb[q * 4096 + (ks + 4) * 512];
        }
    }

    // all s_w reads complete -> reuse as fp32 output staging [c2][r_l4][1024]
    __syncthreads();
    float* s_o = (float*)s_w;

#pragma unroll
    for (int q = 0; q < 2; ++q) {
        const int w = half * 32 + q * 16 + ln;
        float o0[4], o1[4];
#pragma unroll
        for (int r = 0; r < 4; ++r) {
            const int vv = lg * 4 + r;
            float p[9], mx = -1e30f;
#pragma unroll
            for (int k = 0; k < 9; ++k) {
                p[k] = acc[k][q][r] + s_bias[k][vv];
                mx = fmaxf(mx, p[k]);
            }
            float sum = 0.f;
#pragma unroll
            for (int k = 0; k < 9; ++k) { p[k] = __expf(p[k] - mx); sum += p[k]; }
            float inv = 1.0f / sum;
            float a0 = 0.f, a1 = 0.f;
#pragma unroll
            for (int k = 0; k < 9; ++k) {
                const int dy = k / 3, dx = k % 3;
                a0 += p[k] * s_fl[0][r_l + dy][w + dx];
                a1 += p[k] * s_fl[1][r_l + dy][w + dx];
            }
            o0[r] = a0 * inv; o1[r] = a1 * inv;
        }
        *(f32x4*)&s_o[(0 * 4 + r_l) * 1024 + w * 16 + lg * 4] = (f32x4){o0[0], o0[1], o0[2], o0[3]};
        *(f32x4*)&s_o[(1 * 4 + r_l) * 1024 + w * 16 + lg * 4] = (f32x4){o1[0], o1[1], o1[2], o1[3]};
    }
    __syncthreads();

    // cooperative lane-contiguous store: each wave instruction covers 1KB.
    for (int i = tid; i < 2048; i += 512) {
        const int idx = i * 4;           // flat float index into s_o
        const int row = idx >> 10;       // 0..7: c = row>>2, rl = row&3
        const int col = idx & 1023;
        const int c = row >> 2, rl = row & 3;
        f32x4 v = *(const f32x4*)&s_o[idx];
        *(f32x4*)(out + ((size_t)(n * 2 + c) * 1024 + (hg * 4 + rl) * 16 + uvt) * 1024 + col) = v;
    }
}

// ---------------------------------------------------------------------------
extern "C" void kernel_launch(void* const* d_in, const int* in_sizes, int n_in,
                              void* d_out, int out_size, void* d_ws, size_t ws_size,
                              hipStream_t stream) {
    const float* img   = (const float*)d_in[0];
    const float* fh_w1 = (const float*)d_in[1];
    const float* fh_b1 = (const float*)d_in[2];
    const float* fh_g  = (const float*)d_in[3];
    const float* fh_be = (const float*)d_in[4];
    const float* fh_w2 = (const float*)d_in[5];
    const float* fh_b2 = (const float*)d_in[6];
    const float* mk_w1 = (const float*)d_in[7];
    const float* mk_b1 = (const float*)d_in[8];
    const float* mk_g  = (const float*)d_in[9];
    const float* mk_be = (const float*)d_in[10];
    const float* mk_w2 = (const float*)d_in[11];
    const float* mk_b2 = (const float*)d_in[12];
    float* out = (float*)d_out;

    char* p = (char*)d_ws;
    unsigned short* w2f    = (unsigned short*)p;  p += (size_t)1179648;
    unsigned short* w1f    = (unsigned short*)p;  p += (size_t)663552;
    unsigned short* imgT   = (unsigned short*)p;  p += (size_t)4194304;
    unsigned short* m_frag = (unsigned short*)p;  p += (size_t)8388608;
    float* h_pre  = (float*)p;  p += (size_t)131072;
    float* flow8  = (float*)p;  p += (size_t)131072;
    float* ps_s   = (float*)p;  p += (size_t)280576;
    float* ps_s2  = (float*)p;  p += (size_t)280576;
    float* ab_m   = (float*)p;  p += 2048;
    float* ab_h   = (float*)p;  p += 64;

    prep_all<<<2560, 256, 0, stream>>>(img, mk_w1, fh_w1, mk_w2, imgT, w1f, w2f);
    conv1_mfma<<<512, 512, 0, stream>>>(imgT, w1f, mk_b1, fh_b1, m_frag, h_pre, ps_s, ps_s2);
    bn_final2<<<1, 320, 0, stream>>>(ps_s, ps_s2, mk_g, mk_be, fh_g, fh_be, ab_m, ab_h);
    bnrelu_flow<<<2176, 256, 0, stream>>>(m_frag, ab_m, h_pre, ab_h, fh_w2, fh_b2, flow8);
    mask_combine_mfma<<<1024, 512, 0, stream>>>(m_frag, w2f, mk_b2, flow8, out);
}

// Round 11
// 91.376 us; speedup vs baseline: 1.2709x; 1.1578x over previous
//
#include <hip/hip_runtime.h>
#include <hip/hip_bf16.h>

#define N_B   4
#define C_IN  128
#define HWSZ  4096
#define C_M   256

typedef __attribute__((ext_vector_type(8))) short          s16x8;   // bf16x8 frag (4 VGPR)
typedef __attribute__((ext_vector_type(8))) unsigned short u16x8;
typedef __attribute__((ext_vector_type(4))) unsigned short u16x4;
typedef __attribute__((ext_vector_type(4))) float          f32x4;

__device__ __forceinline__ unsigned short f2bf(float f) {
    union { float f; unsigned u; } v; v.f = f;
    unsigned r = v.u + 0x7fffu + ((v.u >> 16) & 1u);   // RNE
    return (unsigned short)(r >> 16);
}
__device__ __forceinline__ float bf2f(unsigned short u) {
    union { unsigned u; float f; } v; v.u = ((unsigned)u) << 16; return v.f;
}

// ---------------------------------------------------------------------------
// K1: fused prep. Blocks 0..255: img transpose (n,ci,h,w)->bf16 (n,h,w,ci).
// Blocks 256..2559: fragment-ordered weights.
//  w1f[z2][cc4][tap9][g9][lane64][j8]; row=g*16+(lane&15), ci=cc*32+(lane>>4)*8+j
//  w2f[uvt16][k9][ks8][lg4][ln16][j8] = 0.25*mk_w2[(k*256+uvt*16+ln)*256+ks*32+lg*8+j]
// ---------------------------------------------------------------------------
__global__ void __launch_bounds__(256)
prep_all(const float* __restrict__ img,
         const float* __restrict__ mk_w1, const float* __restrict__ fh_w1,
         const float* __restrict__ mk_w2,
         unsigned short* __restrict__ imgT,
         unsigned short* __restrict__ w1f, unsigned short* __restrict__ w2f)
{
    __shared__ float s[128][65];
    const int b = blockIdx.x;
    if (b < 256) {
        const int n = b >> 6, h = b & 63;
        const float* src = img + (size_t)n * C_IN * HWSZ + h * 64;
        for (int i = threadIdx.x; i < 128 * 64; i += 256) {
            int ci = i >> 6, w = i & 63;
            s[ci][w] = src[(size_t)ci * HWSZ + w];
        }
        __syncthreads();
        unsigned short* dst = imgT + ((size_t)(n * 64 + h) * 64) * 128;
        for (int i = threadIdx.x; i < 64 * 128; i += 256) {
            int w = i >> 7, ci = i & 127;
            dst[(size_t)w * 128 + ci] = f2bf(s[ci][w]);
        }
        return;
    }
    int i = (b - 256) * 256 + threadIdx.x;
    if (i < 2304 * 256) {
        int uvt = i / 36864;
        int r   = i - uvt * 36864;
        int k   = r / 4096;
        int r2  = r - k * 4096;
        int ks  = r2 >> 9;
        int lg  = (r2 >> 7) & 3;
        int ln  = (r2 >> 3) & 15;
        int j   = r2 & 7;
        w2f[i] = f2bf(0.25f * mk_w2[(size_t)(k * 256 + uvt * 16 + ln) * 256 + ks * 32 + lg * 8 + j]);
    }
    if (i < 2 * 4 * 9 * 9 * 512) {
        int z   = i / 165888;
        int r   = i - z * 165888;
        int cc  = r / 41472;
        int r2  = r - cc * 41472;
        int tap = r2 / 4608;
        int r3  = r2 - tap * 4608;
        int g   = r3 / 512;
        int r4  = r3 - g * 512;
        int lane = r4 >> 3, j = r4 & 7;
        int lg = lane >> 4, ln = lane & 15;
        int row = g * 16 + ln;
        int ci  = cc * 32 + lg * 8 + j;
        float w = 0.f;
        if (z == 0) {
            if (row < 128)      w = mk_w1[((size_t)row * C_IN + ci) * 9 + tap];
            else if (row < 130) w = fh_w1[((size_t)(row - 128) * C_IN + ci) * 9 + tap];
        } else {
            if (row < 128)      w = mk_w1[((size_t)(128 + row) * C_IN + ci) * 9 + tap];
        }
        w1f[i] = f2bf(w);
    }
}

// ---------------------------------------------------------------------------
// K2: conv1 implicit-GEMM 3x3 (unchanged, known-good).
// ---------------------------------------------------------------------------
__global__ void __launch_bounds__(512, 4)
conv1_mfma(const unsigned short* __restrict__ imgT,
           const unsigned short* __restrict__ w1f,
           const float* __restrict__ mk_b1, const float* __restrict__ fh_b1,
           unsigned short* __restrict__ m_frag, float* __restrict__ h_pre,
           float* __restrict__ ps_s, float* __restrict__ ps_s2)
{
    __shared__ unsigned short s_img[3][66][40];   // 15,840 B
    __shared__ float s_bias[144];
    __shared__ float s_ps[2][144], s_ps2[2][144];

    const int hw = blockIdx.x;
    const int xcd = hw & 7, slot = hw >> 3;
    const int lid = xcd * 64 + slot;
    const int n = lid >> 7, h = (lid >> 1) & 63, z = lid & 1;
    const int hn = n * 64 + h;

    const int tid = threadIdx.x;
    const int wv = tid >> 6, lane = tid & 63;
    const int lg = lane >> 4, ln = lane & 15;
    const int gq = wv >> 1, half = wv & 1;
    const int g0 = z ? (gq * 2) : ((int[4]){0, 3, 5, 7})[gq];
    const int gn = z ? 2 : ((int[4]){3, 2, 2, 2})[gq];

    if (tid < 144) {
        float b = 0.f;
        if (z == 0) {
            if (tid < 128)      b = mk_b1[tid];
            else if (tid < 130) b = fh_b1[tid - 128];
        } else if (tid < 128)   b = mk_b1[128 + tid];
        s_bias[tid] = b;
    }

    f32x4 acc[3][2];
#pragma unroll
    for (int g = 0; g < 3; ++g)
#pragma unroll
        for (int q = 0; q < 2; ++q) acc[g][q] = (f32x4){0.f, 0.f, 0.f, 0.f};

    for (int cc = 0; cc < 4; ++cc) {
        __syncthreads();
        for (int i = tid; i < 3 * 66 * 4; i += 512) {
            int r = i / 264;
            int rem = i - r * 264;
            int c = rem >> 2, un = rem & 3;
            int gy = h - 1 + r, gx = c - 1;
            u16x8 v = {0, 0, 0, 0, 0, 0, 0, 0};
            if ((unsigned)gy < 64u && (unsigned)gx < 64u)
                v = *(const u16x8*)&imgT[((size_t)((n * 64 + gy) * 64 + gx)) * 128 + cc * 32 + un * 8];
            *(u16x8*)&s_img[r][c][un * 8] = v;
        }
        __syncthreads();

        const unsigned short* wfp = w1f + (size_t)(z * 4 + cc) * 81 * 512 + lane * 8;
#pragma unroll
        for (int tap = 0; tap < 9; ++tap) {
            const int dy = tap / 3, dx = tap % 3;
            s16x8 bf[2];
#pragma unroll
            for (int q = 0; q < 2; ++q)
                bf[q] = *(const s16x8*)&s_img[dy][half * 32 + q * 16 + ln + dx][lg * 8];
#pragma unroll
            for (int gi = 0; gi < 3; ++gi) {
                if (gi < gn) {
                    s16x8 af = *(const s16x8*)&wfp[(size_t)(tap * 9 + g0 + gi) * 512];
#pragma unroll
                    for (int q = 0; q < 2; ++q)
                        acc[gi][q] = __builtin_amdgcn_mfma_f32_16x16x32_bf16(af, bf[q], acc[gi][q], 0, 0, 0);
                }
            }
        }
    }

    // epilogue: stores + per-channel partial stats
#pragma unroll
    for (int gi = 0; gi < 3; ++gi) {
        if (gi >= gn) continue;
        const int g = g0 + gi;
        float v[2][4];
#pragma unroll
        for (int q = 0; q < 2; ++q)
#pragma unroll
            for (int r = 0; r < 4; ++r)
                v[q][r] = acc[gi][q][r] + s_bias[g * 16 + lg * 4 + r];
        // stores
#pragma unroll
        for (int q = 0; q < 2; ++q) {
            const int px  = half * 32 + q * 16 + ln;
            const int pxg = h * 4 + half * 2 + q;
            if (z == 0 && g == 8) {
                if (lg == 0) {
#pragma unroll
                    for (int r = 0; r < 2; ++r)
                        h_pre[((size_t)(n * 2 + r)) * HWSZ + h * 64 + px] = v[q][r];
                }
            } else {
                u16x4 vv;
#pragma unroll
                for (int r = 0; r < 4; ++r) vv[r] = f2bf(v[q][r]);
                int ks  = z * 4 + (g >> 1);
                int lgp = ((g & 1) * 2 + (lg >> 1)) & 3;
                size_t off = ((((size_t)(n * 256 + pxg) * 8 + ks) * 4 + lgp) * 128) + ln * 8 + (lg & 1) * 4;
                *(u16x4*)&m_frag[off] = vv;
            }
        }
        // partial stats
#pragma unroll
        for (int r = 0; r < 4; ++r) {
            float s  = v[0][r] + v[1][r];
            float s2 = v[0][r] * v[0][r] + v[1][r] * v[1][r];
#pragma unroll
            for (int off = 1; off < 16; off <<= 1) {
                s  += __shfl_xor(s,  off, 64);
                s2 += __shfl_xor(s2, off, 64);
            }
            if (ln == 0) {
                s_ps[half][g * 16 + lg * 4 + r]  = s;
                s_ps2[half][g * 16 + lg * 4 + r] = s2;
            }
        }
    }
    __syncthreads();
    const int nch = z ? 128 : 130;
    if (tid < nch) {
        const int idx = z * 146 + tid;
        ps_s[(size_t)idx * 256 + hn]  = s_ps[0][tid] + s_ps[1][tid];
        ps_s2[(size_t)idx * 256 + hn] = s_ps2[0][tid] + s_ps2[1][tid];
    }
}

// ---------------------------------------------------------------------------
// K3: final BN stat reduction, parallelized: one block per channel (258),
// 64 threads, shuffle reduce.
// ---------------------------------------------------------------------------
__global__ void __launch_bounds__(64)
bn_final2(const float* __restrict__ ps_s, const float* __restrict__ ps_s2,
          const float* __restrict__ mk_g, const float* __restrict__ mk_be,
          const float* __restrict__ fh_g, const float* __restrict__ fh_be,
          float* __restrict__ ab_m, float* __restrict__ ab_h)
{
    const int b = blockIdx.x;
    const int idx = (b < 256) ? ((b >> 7) * 146 + (b & 127)) : (128 + (b - 256));
    const int t = threadIdx.x;
    float S = 0.f, S2 = 0.f;
    const float* p1 = ps_s  + (size_t)idx * 256;
    const float* p2 = ps_s2 + (size_t)idx * 256;
    for (int i = t; i < 256; i += 64) { S += p1[i]; S2 += p2[i]; }
#pragma unroll
    for (int off = 32; off > 0; off >>= 1) {
        S += __shfl_down(S, off, 64); S2 += __shfl_down(S2, off, 64);
    }
    if (t == 0) {
        const float inv = 1.0f / (float)(N_B * HWSZ);
        float mu = S * inv;
        float var = S2 * inv - mu * mu;
        float r = rsqrtf(var + 1e-5f);
        if (b < 256) {
            float a = mk_g[b] * r;
            ab_m[2 * b] = a; ab_m[2 * b + 1] = mk_be[b] - mu * a;
        } else {
            int c = b - 256;
            float a = fh_g[c] * r;
            ab_h[2 * c] = a; ab_h[2 * c + 1] = fh_be[c] - mu * a;
        }
    }
}

// ---------------------------------------------------------------------------
// K4: blocks 0..2047 in-place BN+ReLU on m_frag; blocks 2048..2175 flow conv2.
// ---------------------------------------------------------------------------
__global__ void __launch_bounds__(256)
bnrelu_flow(unsigned short* __restrict__ m_frag, const float* __restrict__ ab,
            const float* __restrict__ hpre, const float* __restrict__ ab_h,
            const float* __restrict__ w2, const float* __restrict__ b2,
            float* __restrict__ flow8)
{
    __shared__ float s_ab[512];
    const int t = threadIdx.x;
    if (blockIdx.x < 2048) {
        s_ab[t] = ab[t]; s_ab[256 + t] = ab[256 + t];
        __syncthreads();
        const unsigned u = blockIdx.x * 256 + t;
        const int lg = (u >> 4) & 3, ks = (u >> 7) & 7;
        const int cb = ks * 32 + lg * 8;
        u16x8 v = *(const u16x8*)&m_frag[(size_t)u * 8];
        u16x8 o;
#pragma unroll
        for (int j = 0; j < 8; ++j) {
            float a = s_ab[2 * (cb + j)], b = s_ab[2 * (cb + j) + 1];
            o[j] = f2bf(fmaxf(a * bf2f(v[j]) + b, 0.f));
        }
        *(u16x8*)&m_frag[(size_t)u * 8] = o;
        return;
    }
    int idx = (blockIdx.x - 2048) * 256 + t;
    int w = idx & 63, h = (idx >> 6) & 63, co = (idx >> 12) & 1, n = idx >> 13;
    float acc = b2[co];
#pragma unroll
    for (int ci = 0; ci < 2; ++ci) {
        float a = ab_h[2 * ci], b = ab_h[2 * ci + 1];
        const float* p = hpre + (size_t)(n * 2 + ci) * HWSZ;
        const float* wp = &w2[(co * 2 + ci) * 9];
#pragma unroll
        for (int dy = 0; dy < 3; ++dy)
#pragma unroll
            for (int dx = 0; dx < 3; ++dx) {
                int gy = h + dy - 1, gx = w + dx - 1;
                float v = 0.f;
                if ((unsigned)gy < 64u && (unsigned)gx < 64u)
                    v = fmaxf(a * p[gy * 64 + gx] + b, 0.f);
                acc += wp[dy * 3 + dx] * v;
            }
    }
    flow8[idx] = acc * 8.0f;
}

// ---------------------------------------------------------------------------
// K5: fused 1x1-conv GEMM + bias + softmax(9) + convex upsample.
// EXACT R9 structure (known-good numerics) with two occupancy edits:
//  - __launch_bounds__(512, 4): target 128 regs/wave -> 2 blocks/CU
//    = 4 waves/SIMD (R9 at (512,3) was 152 regs -> 1 block/CU).
//  - bq prefetch 4-deep -> 2-deep rolling (saves 16 VGPRs; in-loop peak
//    acc 72 AGPR + bq 16 + af 4 + addr ~14 = ~106 < 128).
// Grid 1024, id = hg + 16*uvt + 256*n (rows pin to XCDs).
// ---------------------------------------------------------------------------
__global__ void __launch_bounds__(512, 4)
mask_combine_mfma(const unsigned short* __restrict__ m_frag,
                  const unsigned short* __restrict__ w2f,
                  const float* __restrict__ mk_b2,
                  const float* __restrict__ flow8,
                  float* __restrict__ out)
{
    __shared__ unsigned short s_w[36864];       // 73,728 B; dead after MFMA
    __shared__ float s_fl[2][6][66];            // 3,168 B
    __shared__ float s_bias[9][16];             // 576 B

    const int id = blockIdx.x;
    const int hg = id & 15, uvt = (id >> 4) & 15, n = id >> 8;

    const int tid = threadIdx.x;
    const int wv = tid >> 6, lane = tid & 63;
    const int lg = lane >> 4, ln = lane & 15;
    const int r_l = wv >> 1, half = wv & 1;
    const int h = hg * 4 + r_l;

    {
        const u16x8* wsrc = (const u16x8*)(w2f + (size_t)uvt * 36864);
        u16x8* wdst = (u16x8*)s_w;
        for (int i = tid; i < 4608; i += 512) wdst[i] = wsrc[i];
    }
    for (int i = tid; i < 2 * 6 * 66; i += 512) {
        int c = i / 396, rem = i - c * 396, r = rem / 66, col = rem - r * 66;
        int gy = hg * 4 - 1 + r, gx = col - 1;
        float v = 0.f;
        if ((unsigned)gy < 64u && (unsigned)gx < 64u)
            v = flow8[((size_t)(n * 2 + c)) * HWSZ + gy * 64 + gx];
        s_fl[c][r][col] = v;
    }
    if (tid < 144) s_bias[tid >> 4][tid & 15] = 0.25f * mk_b2[(tid >> 4) * 256 + uvt * 16 + (tid & 15)];
    __syncthreads();

    const unsigned short* wk0 = s_w + lg * 128 + ln * 8;
    const unsigned short* mb = m_frag + (size_t)(n * 256 + h * 4 + half * 2) * 4096 + lg * 128 + ln * 8;

    f32x4 acc[9][2];
#pragma unroll
    for (int k = 0; k < 9; ++k)
#pragma unroll
        for (int q = 0; q < 2; ++q) acc[k][q] = (f32x4){0.f, 0.f, 0.f, 0.f};

    // rolling 2-deep B prefetch (4 loads in flight)
    s16x8 bq[2][2];
#pragma unroll
    for (int d = 0; d < 2; ++d)
#pragma unroll
        for (int q = 0; q < 2; ++q) bq[d][q] = *(const s16x8*)&mb[q * 4096 + d * 512];

#pragma unroll
    for (int ks = 0; ks < 8; ++ks) {
        const int d = ks & 1;
        const unsigned short* wk = wk0 + ks * 512;
#pragma unroll
        for (int k = 0; k < 9; ++k) {
            s16x8 af = *(const s16x8*)&wk[k * 4096];
#pragma unroll
            for (int q = 0; q < 2; ++q)
                acc[k][q] = __builtin_amdgcn_mfma_f32_16x16x32_bf16(af, bq[d][q], acc[k][q], 0, 0, 0);
        }
        if (ks < 6) {
#pragma unroll
            for (int q = 0; q < 2; ++q)
                bq[d][q] = *(const s16x8*)&mb[q * 4096 + (ks + 2) * 512];
        }
    }

    // all s_w reads complete -> reuse as fp32 output staging [c2][r_l4][1024]
    __syncthreads();
    float* s_o = (float*)s_w;

#pragma unroll
    for (int q = 0; q < 2; ++q) {
        const int w = half * 32 + q * 16 + ln;
        float o0[4], o1[4];
#pragma unroll
        for (int r = 0; r < 4; ++r) {
            const int vv = lg * 4 + r;
            float p[9], mx = -1e30f;
#pragma unroll
            for (int k = 0; k < 9; ++k) {
                p[k] = acc[k][q][r] + s_bias[k][vv];
                mx = fmaxf(mx, p[k]);
            }
            float sum = 0.f;
#pragma unroll
            for (int k = 0; k < 9; ++k) { p[k] = __expf(p[k] - mx); sum += p[k]; }
            float inv = 1.0f / sum;
            float a0 = 0.f, a1 = 0.f;
#pragma unroll
            for (int k = 0; k < 9; ++k) {
                const int dy = k / 3, dx = k % 3;
                a0 += p[k] * s_fl[0][r_l + dy][w + dx];
                a1 += p[k] * s_fl[1][r_l + dy][w + dx];
            }
            o0[r] = a0 * inv; o1[r] = a1 * inv;
        }
        *(f32x4*)&s_o[(0 * 4 + r_l) * 1024 + w * 16 + lg * 4] = (f32x4){o0[0], o0[1], o0[2], o0[3]};
        *(f32x4*)&s_o[(1 * 4 + r_l) * 1024 + w * 16 + lg * 4] = (f32x4){o1[0], o1[1], o1[2], o1[3]};
    }
    __syncthreads();

    // cooperative lane-contiguous store: each wave instruction covers 1KB.
    for (int i = tid; i < 2048; i += 512) {
        const int idx = i * 4;           // flat float index into s_o
        const int row = idx >> 10;       // 0..7: c = row>>2, rl = row&3
        const int col = idx & 1023;
        const int c = row >> 2, rl = row & 3;
        f32x4 v = *(const f32x4*)&s_o[idx];
        *(f32x4*)(out + ((size_t)(n * 2 + c) * 1024 + (hg * 4 + rl) * 16 + uvt) * 1024 + col) = v;
    }
}

// ---------------------------------------------------------------------------
extern "C" void kernel_launch(void* const* d_in, const int* in_sizes, int n_in,
                              void* d_out, int out_size, void* d_ws, size_t ws_size,
                              hipStream_t stream) {
    const float* img   = (const float*)d_in[0];
    const float* fh_w1 = (const float*)d_in[1];
    const float* fh_b1 = (const float*)d_in[2];
    const float* fh_g  = (const float*)d_in[3];
    const float* fh_be = (const float*)d_in[4];
    const float* fh_w2 = (const float*)d_in[5];
    const float* fh_b2 = (const float*)d_in[6];
    const float* mk_w1 = (const float*)d_in[7];
    const float* mk_b1 = (const float*)d_in[8];
    const float* mk_g  = (const float*)d_in[9];
    const float* mk_be = (const float*)d_in[10];
    const float* mk_w2 = (const float*)d_in[11];
    const float* mk_b2 = (const float*)d_in[12];
    float* out = (float*)d_out;

    char* p = (char*)d_ws;
    unsigned short* w2f    = (unsigned short*)p;  p += (size_t)1179648;
    unsigned short* w1f    = (unsigned short*)p;  p += (size_t)663552;
    unsigned short* imgT   = (unsigned short*)p;  p += (size_t)4194304;
    unsigned short* m_frag = (unsigned short*)p;  p += (size_t)8388608;
    float* h_pre  = (float*)p;  p += (size_t)131072;
    float* flow8  = (float*)p;  p += (size_t)131072;
    float* ps_s   = (float*)p;  p += (size_t)280576;
    float* ps_s2  = (float*)p;  p += (size_t)280576;
    float* ab_m   = (float*)p;  p += 2048;
    float* ab_h   = (float*)p;  p += 64;

    prep_all<<<2560, 256, 0, stream>>>(img, mk_w1, fh_w1, mk_w2, imgT, w1f, w2f);
    conv1_mfma<<<512, 512, 0, stream>>>(imgT, w1f, mk_b1, fh_b1, m_frag, h_pre, ps_s, ps_s2);
    bn_final2<<<258, 64, 0, stream>>>(ps_s, ps_s2, mk_g, mk_be, fh_g, fh_be, ab_m, ab_h);
    bnrelu_flow<<<2176, 256, 0, stream>>>(m_frag, ab_m, h_pre, ab_h, fh_w2, fh_b2, flow8);
    mask_combine_mfma<<<1024, 512, 0, stream>>>(m_frag, w2f, mk_b2, flow8, out);
}

// Round 12
// 81.656 us; speedup vs baseline: 1.4222x; 1.1190x over previous
//
#include <hip/hip_runtime.h>
#include <hip/hip_bf16.h>

#define N_B   4
#define C_IN  128
#define HWSZ  4096
#define C_M   256

typedef __attribute__((ext_vector_type(8))) short          s16x8;   // bf16x8 frag (4 VGPR)
typedef __attribute__((ext_vector_type(8))) unsigned short u16x8;
typedef __attribute__((ext_vector_type(4))) unsigned short u16x4;
typedef __attribute__((ext_vector_type(4))) float          f32x4;

__device__ __forceinline__ unsigned short f2bf(float f) {
    union { float f; unsigned u; } v; v.f = f;
    unsigned r = v.u + 0x7fffu + ((v.u >> 16) & 1u);   // RNE
    return (unsigned short)(r >> 16);
}
__device__ __forceinline__ float bf2f(unsigned short u) {
    union { unsigned u; float f; } v; v.u = ((unsigned)u) << 16; return v.f;
}

// ---------------------------------------------------------------------------
// K1: fused prep. Blocks 0..255: img transpose (n,ci,h,w)->bf16 (n,h,w,ci).
// Blocks 256..2559: fragment-ordered weights.
//  w1f[z2][cc4][tap9][g9][lane64][j8]; row=g*16+(lane&15), ci=cc*32+(lane>>4)*8+j
//  w2f[uvt16][k9][ks8][lg4][ln16][j8] = 0.25*mk_w2[(k*256+uvt*16+ln)*256+ks*32+lg*8+j]
// ---------------------------------------------------------------------------
__global__ void __launch_bounds__(256)
prep_all(const float* __restrict__ img,
         const float* __restrict__ mk_w1, const float* __restrict__ fh_w1,
         const float* __restrict__ mk_w2,
         unsigned short* __restrict__ imgT,
         unsigned short* __restrict__ w1f, unsigned short* __restrict__ w2f)
{
    __shared__ float s[128][65];
    const int b = blockIdx.x;
    if (b < 256) {
        const int n = b >> 6, h = b & 63;
        const float* src = img + (size_t)n * C_IN * HWSZ + h * 64;
        for (int i = threadIdx.x; i < 128 * 64; i += 256) {
            int ci = i >> 6, w = i & 63;
            s[ci][w] = src[(size_t)ci * HWSZ + w];
        }
        __syncthreads();
        unsigned short* dst = imgT + ((size_t)(n * 64 + h) * 64) * 128;
        for (int i = threadIdx.x; i < 64 * 128; i += 256) {
            int w = i >> 7, ci = i & 127;
            dst[(size_t)w * 128 + ci] = f2bf(s[ci][w]);
        }
        return;
    }
    int i = (b - 256) * 256 + threadIdx.x;
    if (i < 2304 * 256) {
        int uvt = i / 36864;
        int r   = i - uvt * 36864;
        int k   = r / 4096;
        int r2  = r - k * 4096;
        int ks  = r2 >> 9;
        int lg  = (r2 >> 7) & 3;
        int ln  = (r2 >> 3) & 15;
        int j   = r2 & 7;
        w2f[i] = f2bf(0.25f * mk_w2[(size_t)(k * 256 + uvt * 16 + ln) * 256 + ks * 32 + lg * 8 + j]);
    }
    if (i < 2 * 4 * 9 * 9 * 512) {
        int z   = i / 165888;
        int r   = i - z * 165888;
        int cc  = r / 41472;
        int r2  = r - cc * 41472;
        int tap = r2 / 4608;
        int r3  = r2 - tap * 4608;
        int g   = r3 / 512;
        int r4  = r3 - g * 512;
        int lane = r4 >> 3, j = r4 & 7;
        int lg = lane >> 4, ln = lane & 15;
        int row = g * 16 + ln;
        int ci  = cc * 32 + lg * 8 + j;
        float w = 0.f;
        if (z == 0) {
            if (row < 128)      w = mk_w1[((size_t)row * C_IN + ci) * 9 + tap];
            else if (row < 130) w = fh_w1[((size_t)(row - 128) * C_IN + ci) * 9 + tap];
        } else {
            if (row < 128)      w = mk_w1[((size_t)(128 + row) * C_IN + ci) * 9 + tap];
        }
        w1f[i] = f2bf(w);
    }
}

// ---------------------------------------------------------------------------
// K2: conv1 implicit-GEMM 3x3 (unchanged, known-good).
// ---------------------------------------------------------------------------
__global__ void __launch_bounds__(512, 4)
conv1_mfma(const unsigned short* __restrict__ imgT,
           const unsigned short* __restrict__ w1f,
           const float* __restrict__ mk_b1, const float* __restrict__ fh_b1,
           unsigned short* __restrict__ m_frag, float* __restrict__ h_pre,
           float* __restrict__ ps_s, float* __restrict__ ps_s2)
{
    __shared__ unsigned short s_img[3][66][40];   // 15,840 B
    __shared__ float s_bias[144];
    __shared__ float s_ps[2][144], s_ps2[2][144];

    const int hw = blockIdx.x;
    const int xcd = hw & 7, slot = hw >> 3;
    const int lid = xcd * 64 + slot;
    const int n = lid >> 7, h = (lid >> 1) & 63, z = lid & 1;
    const int hn = n * 64 + h;

    const int tid = threadIdx.x;
    const int wv = tid >> 6, lane = tid & 63;
    const int lg = lane >> 4, ln = lane & 15;
    const int gq = wv >> 1, half = wv & 1;
    const int g0 = z ? (gq * 2) : ((int[4]){0, 3, 5, 7})[gq];
    const int gn = z ? 2 : ((int[4]){3, 2, 2, 2})[gq];

    if (tid < 144) {
        float b = 0.f;
        if (z == 0) {
            if (tid < 128)      b = mk_b1[tid];
            else if (tid < 130) b = fh_b1[tid - 128];
        } else if (tid < 128)   b = mk_b1[128 + tid];
        s_bias[tid] = b;
    }

    f32x4 acc[3][2];
#pragma unroll
    for (int g = 0; g < 3; ++g)
#pragma unroll
        for (int q = 0; q < 2; ++q) acc[g][q] = (f32x4){0.f, 0.f, 0.f, 0.f};

    for (int cc = 0; cc < 4; ++cc) {
        __syncthreads();
        for (int i = tid; i < 3 * 66 * 4; i += 512) {
            int r = i / 264;
            int rem = i - r * 264;
            int c = rem >> 2, un = rem & 3;
            int gy = h - 1 + r, gx = c - 1;
            u16x8 v = {0, 0, 0, 0, 0, 0, 0, 0};
            if ((unsigned)gy < 64u && (unsigned)gx < 64u)
                v = *(const u16x8*)&imgT[((size_t)((n * 64 + gy) * 64 + gx)) * 128 + cc * 32 + un * 8];
            *(u16x8*)&s_img[r][c][un * 8] = v;
        }
        __syncthreads();

        const unsigned short* wfp = w1f + (size_t)(z * 4 + cc) * 81 * 512 + lane * 8;
#pragma unroll
        for (int tap = 0; tap < 9; ++tap) {
            const int dy = tap / 3, dx = tap % 3;
            s16x8 bf[2];
#pragma unroll
            for (int q = 0; q < 2; ++q)
                bf[q] = *(const s16x8*)&s_img[dy][half * 32 + q * 16 + ln + dx][lg * 8];
#pragma unroll
            for (int gi = 0; gi < 3; ++gi) {
                if (gi < gn) {
                    s16x8 af = *(const s16x8*)&wfp[(size_t)(tap * 9 + g0 + gi) * 512];
#pragma unroll
                    for (int q = 0; q < 2; ++q)
                        acc[gi][q] = __builtin_amdgcn_mfma_f32_16x16x32_bf16(af, bf[q], acc[gi][q], 0, 0, 0);
                }
            }
        }
    }

    // epilogue: stores + per-channel partial stats
#pragma unroll
    for (int gi = 0; gi < 3; ++gi) {
        if (gi >= gn) continue;
        const int g = g0 + gi;
        float v[2][4];
#pragma unroll
        for (int q = 0; q < 2; ++q)
#pragma unroll
            for (int r = 0; r < 4; ++r)
                v[q][r] = acc[gi][q][r] + s_bias[g * 16 + lg * 4 + r];
        // stores
#pragma unroll
        for (int q = 0; q < 2; ++q) {
            const int px  = half * 32 + q * 16 + ln;
            const int pxg = h * 4 + half * 2 + q;
            if (z == 0 && g == 8) {
                if (lg == 0) {
#pragma unroll
                    for (int r = 0; r < 2; ++r)
                        h_pre[((size_t)(n * 2 + r)) * HWSZ + h * 64 + px] = v[q][r];
                }
            } else {
                u16x4 vv;
#pragma unroll
                for (int r = 0; r < 4; ++r) vv[r] = f2bf(v[q][r]);
                int ks  = z * 4 + (g >> 1);
                int lgp = ((g & 1) * 2 + (lg >> 1)) & 3;
                size_t off = ((((size_t)(n * 256 + pxg) * 8 + ks) * 4 + lgp) * 128) + ln * 8 + (lg & 1) * 4;
                *(u16x4*)&m_frag[off] = vv;
            }
        }
        // partial stats
#pragma unroll
        for (int r = 0; r < 4; ++r) {
            float s  = v[0][r] + v[1][r];
            float s2 = v[0][r] * v[0][r] + v[1][r] * v[1][r];
#pragma unroll
            for (int off = 1; off < 16; off <<= 1) {
                s  += __shfl_xor(s,  off, 64);
                s2 += __shfl_xor(s2, off, 64);
            }
            if (ln == 0) {
                s_ps[half][g * 16 + lg * 4 + r]  = s;
                s_ps2[half][g * 16 + lg * 4 + r] = s2;
            }
        }
    }
    __syncthreads();
    const int nch = z ? 128 : 130;
    if (tid < nch) {
        const int idx = z * 146 + tid;
        ps_s[(size_t)idx * 256 + hn]  = s_ps[0][tid] + s_ps[1][tid];
        ps_s2[(size_t)idx * 256 + hn] = s_ps2[0][tid] + s_ps2[1][tid];
    }
}

// ---------------------------------------------------------------------------
// K3: final BN stat reduction, one block per channel (258), 64 thr.
// ---------------------------------------------------------------------------
__global__ void __launch_bounds__(64)
bn_final2(const float* __restrict__ ps_s, const float* __restrict__ ps_s2,
          const float* __restrict__ mk_g, const float* __restrict__ mk_be,
          const float* __restrict__ fh_g, const float* __restrict__ fh_be,
          float* __restrict__ ab_m, float* __restrict__ ab_h)
{
    const int b = blockIdx.x;
    const int idx = (b < 256) ? ((b >> 7) * 146 + (b & 127)) : (128 + (b - 256));
    const int t = threadIdx.x;
    float S = 0.f, S2 = 0.f;
    const float* p1 = ps_s  + (size_t)idx * 256;
    const float* p2 = ps_s2 + (size_t)idx * 256;
    for (int i = t; i < 256; i += 64) { S += p1[i]; S2 += p2[i]; }
#pragma unroll
    for (int off = 32; off > 0; off >>= 1) {
        S += __shfl_down(S, off, 64); S2 += __shfl_down(S2, off, 64);
    }
    if (t == 0) {
        const float inv = 1.0f / (float)(N_B * HWSZ);
        float mu = S * inv;
        float var = S2 * inv - mu * mu;
        float r = rsqrtf(var + 1e-5f);
        if (b < 256) {
            float a = mk_g[b] * r;
            ab_m[2 * b] = a; ab_m[2 * b + 1] = mk_be[b] - mu * a;
        } else {
            int c = b - 256;
            float a = fh_g[c] * r;
            ab_h[2 * c] = a; ab_h[2 * c + 1] = fh_be[c] - mu * a;
        }
    }
}

// ---------------------------------------------------------------------------
// K4: blocks 0..2047 in-place BN+ReLU on m_frag; blocks 2048..2175 flow conv2.
// ---------------------------------------------------------------------------
__global__ void __launch_bounds__(256)
bnrelu_flow(unsigned short* __restrict__ m_frag, const float* __restrict__ ab,
            const float* __restrict__ hpre, const float* __restrict__ ab_h,
            const float* __restrict__ w2, const float* __restrict__ b2,
            float* __restrict__ flow8)
{
    __shared__ float s_ab[512];
    const int t = threadIdx.x;
    if (blockIdx.x < 2048) {
        s_ab[t] = ab[t]; s_ab[256 + t] = ab[256 + t];
        __syncthreads();
        const unsigned u = blockIdx.x * 256 + t;
        const int lg = (u >> 4) & 3, ks = (u >> 7) & 7;
        const int cb = ks * 32 + lg * 8;
        u16x8 v = *(const u16x8*)&m_frag[(size_t)u * 8];
        u16x8 o;
#pragma unroll
        for (int j = 0; j < 8; ++j) {
            float a = s_ab[2 * (cb + j)], b = s_ab[2 * (cb + j) + 1];
            o[j] = f2bf(fmaxf(a * bf2f(v[j]) + b, 0.f));
        }
        *(u16x8*)&m_frag[(size_t)u * 8] = o;
        return;
    }
    int idx = (blockIdx.x - 2048) * 256 + t;
    int w = idx & 63, h = (idx >> 6) & 63, co = (idx >> 12) & 1, n = idx >> 13;
    float acc = b2[co];
#pragma unroll
    for (int ci = 0; ci < 2; ++ci) {
        float a = ab_h[2 * ci], b = ab_h[2 * ci + 1];
        const float* p = hpre + (size_t)(n * 2 + ci) * HWSZ;
        const float* wp = &w2[(co * 2 + ci) * 9];
#pragma unroll
        for (int dy = 0; dy < 3; ++dy)
#pragma unroll
            for (int dx = 0; dx < 3; ++dx) {
                int gy = h + dy - 1, gx = w + dx - 1;
                float v = 0.f;
                if ((unsigned)gy < 64u && (unsigned)gx < 64u)
                    v = fmaxf(a * p[gy * 64 + gx] + b, 0.f);
                acc += wp[dy * 3 + dx] * v;
            }
    }
    flow8[idx] = acc * 8.0f;
}

// ---------------------------------------------------------------------------
// K5: fused 1x1-conv GEMM + bias + softmax(9) + convex upsample.
// R12: q=1 redesign. 1024 thr = 16 waves, each wave owns ONE 16-px group x
// all 9 k -> acc[9] = 36 AGPR; in-wave softmax (numerics == R9/R11).
// Peak regs ~95 < 128 -> (1024,4) with no spill, 4 waves/SIMD.
// Block covers 8 rows in 2 passes reusing the staged W tile; dedicated
// 32KB s_o staging (LDS 112KB, 1 block/CU). Exact-32MB contiguous stores.
// Grid 512, id = hg + 8*uvt + 128*n -> id%8 = hg: rows pin to XCDs.
// ---------------------------------------------------------------------------
__global__ void __launch_bounds__(1024, 4)
mask_combine_mfma(const unsigned short* __restrict__ m_frag,
                  const unsigned short* __restrict__ w2f,
                  const float* __restrict__ mk_b2,
                  const float* __restrict__ flow8,
                  float* __restrict__ out)
{
    __shared__ unsigned short s_w[36864];       // 73,728 B
    __shared__ float s_o[8192];                 // 32,768 B output staging
    __shared__ float s_fl[2][10][66];           // 5,280 B
    __shared__ float s_bias[9][16];             // 576 B

    const int id = blockIdx.x;
    const int hg = id & 7, uvt = (id >> 3) & 15, n = id >> 7;

    const int tid = threadIdx.x;
    const int wv = tid >> 6, lane = tid & 63;
    const int lg = lane >> 4, ln = lane & 15;
    const int row_l = wv >> 2, qq = wv & 3;
    const int w = qq * 16 + ln;

    // stage W tile (linear copy)
    {
        const u16x8* wsrc = (const u16x8*)(w2f + (size_t)uvt * 36864);
        u16x8* wdst = (u16x8*)s_w;
        for (int i = tid; i < 4608; i += 1024) wdst[i] = wsrc[i];
    }
    // stage flow rows hg*8-1 .. hg*8+8
    for (int i = tid; i < 2 * 10 * 66; i += 1024) {
        int c = i / 660, rem = i - c * 660, r = rem / 66, col = rem - r * 66;
        int gy = hg * 8 - 1 + r, gx = col - 1;
        float v = 0.f;
        if ((unsigned)gy < 64u && (unsigned)gx < 64u)
            v = flow8[((size_t)(n * 2 + c)) * HWSZ + gy * 64 + gx];
        s_fl[c][r][col] = v;
    }
    if (tid < 144) s_bias[tid >> 4][tid & 15] = 0.25f * mk_b2[(tid >> 4) * 256 + uvt * 16 + (tid & 15)];
    __syncthreads();

    const unsigned short* wk0 = s_w + lg * 128 + ln * 8;

    for (int pass = 0; pass < 2; ++pass) {
        const int h = hg * 8 + pass * 4 + row_l;
        const unsigned short* mb = m_frag + (size_t)(n * 256 + h * 4 + qq) * 4096 + lg * 128 + ln * 8;

        f32x4 acc[9];
#pragma unroll
        for (int k = 0; k < 9; ++k) acc[k] = (f32x4){0.f, 0.f, 0.f, 0.f};

        // rolling 2-deep B prefetch
        s16x8 bq[2];
        bq[0] = *(const s16x8*)&mb[0];
        bq[1] = *(const s16x8*)&mb[512];

#pragma unroll
        for (int ks = 0; ks < 8; ++ks) {
            const int d = ks & 1;
            const unsigned short* wk = wk0 + ks * 512;
#pragma unroll
            for (int k = 0; k < 9; ++k) {
                s16x8 af = *(const s16x8*)&wk[k * 4096];
                acc[k] = __builtin_amdgcn_mfma_f32_16x16x32_bf16(af, bq[d], acc[k], 0, 0, 0);
            }
            if (ks < 6) bq[d] = *(const s16x8*)&mb[(ks + 2) * 512];
        }

        // epilogue: in-wave softmax over 9 k + convex combine -> s_o
#pragma unroll
        for (int r = 0; r < 4; ++r) {
            const int vv = lg * 4 + r;
            float p[9], mx = -1e30f;
#pragma unroll
            for (int k = 0; k < 9; ++k) {
                p[k] = acc[k][r] + s_bias[k][vv];
                mx = fmaxf(mx, p[k]);
            }
            float sum = 0.f;
#pragma unroll
            for (int k = 0; k < 9; ++k) { p[k] = __expf(p[k] - mx); sum += p[k]; }
            float inv = 1.0f / sum;
            float a0 = 0.f, a1 = 0.f;
#pragma unroll
            for (int k = 0; k < 9; ++k) {
                const int dy = k / 3, dx = k % 3;
                a0 += p[k] * s_fl[0][pass * 4 + row_l + dy][w + dx];
                a1 += p[k] * s_fl[1][pass * 4 + row_l + dy][w + dx];
            }
            s_o[(0 * 4 + row_l) * 1024 + w * 16 + lg * 4 + r] = a0 * inv;
            s_o[(1 * 4 + row_l) * 1024 + w * 16 + lg * 4 + r] = a1 * inv;
        }
        __syncthreads();

        // cooperative lane-contiguous store: 8 rows x 4KB, fully dense.
        for (int i = tid; i < 2048; i += 1024) {
            const int idx = i * 4;
            const int row = idx >> 10;       // 0..7: c = row>>2, rl = row&3
            const int col = idx & 1023;
            const int c = row >> 2, rl = row & 3;
            f32x4 v = *(const f32x4*)&s_o[idx];
            *(f32x4*)(out + ((size_t)(n * 2 + c) * 1024 +
                             (hg * 8 + pass * 4 + rl) * 16 + uvt) * 1024 + col) = v;
        }
        __syncthreads();   // protect s_o before next pass overwrites
    }
}

// ---------------------------------------------------------------------------
extern "C" void kernel_launch(void* const* d_in, const int* in_sizes, int n_in,
                              void* d_out, int out_size, void* d_ws, size_t ws_size,
                              hipStream_t stream) {
    const float* img   = (const float*)d_in[0];
    const float* fh_w1 = (const float*)d_in[1];
    const float* fh_b1 = (const float*)d_in[2];
    const float* fh_g  = (const float*)d_in[3];
    const float* fh_be = (const float*)d_in[4];
    const float* fh_w2 = (const float*)d_in[5];
    const float* fh_b2 = (const float*)d_in[6];
    const float* mk_w1 = (const float*)d_in[7];
    const float* mk_b1 = (const float*)d_in[8];
    const float* mk_g  = (const float*)d_in[9];
    const float* mk_be = (const float*)d_in[10];
    const float* mk_w2 = (const float*)d_in[11];
    const float* mk_b2 = (const float*)d_in[12];
    float* out = (float*)d_out;

    char* p = (char*)d_ws;
    unsigned short* w2f    = (unsigned short*)p;  p += (size_t)1179648;
    unsigned short* w1f    = (unsigned short*)p;  p += (size_t)663552;
    unsigned short* imgT   = (unsigned short*)p;  p += (size_t)4194304;
    unsigned short* m_frag = (unsigned short*)p;  p += (size_t)8388608;
    float* h_pre  = (float*)p;  p += (size_t)131072;
    float* flow8  = (float*)p;  p += (size_t)131072;
    float* ps_s   = (float*)p;  p += (size_t)280576;
    float* ps_s2  = (float*)p;  p += (size_t)280576;
    float* ab_m   = (float*)p;  p += 2048;
    float* ab_h   = (float*)p;  p += 64;

    prep_all<<<2560, 256, 0, stream>>>(img, mk_w1, fh_w1, mk_w2, imgT, w1f, w2f);
    conv1_mfma<<<512, 512, 0, stream>>>(imgT, w1f, mk_b1, fh_b1, m_frag, h_pre, ps_s, ps_s2);
    bn_final2<<<258, 64, 0, stream>>>(ps_s, ps_s2, mk_g, mk_be, fh_g, fh_be, ab_m, ab_h);
    bnrelu_flow<<<2176, 256, 0, stream>>>(m_frag, ab_m, h_pre, ab_h, fh_w2, fh_b2, flow8);
    mask_combine_mfma<<<512, 1024, 0, stream>>>(m_frag, w2f, mk_b2, flow8, out);
}